// Round 1
// baseline (135.982 us; speedup 1.0000x reference)
//
#include <hip/hip_runtime.h>
#include <hip/hip_bf16.h>

#define SLEN 4096
#define NH   16
#define DH   64
#define WW   256
#define GMAX 64

typedef unsigned short u16;
typedef unsigned int   u32;
typedef unsigned long long u64;
typedef __attribute__((ext_vector_type(8))) short bf16x8;
typedef __attribute__((ext_vector_type(4))) float f32x4;

#define MFMA16(a,b,c) __builtin_amdgcn_mfma_f32_16x16x32_bf16((a),(b),(c),0,0,0)

static __device__ __forceinline__ int imin(int a, int b) { return a < b ? a : b; }
static __device__ __forceinline__ int imax(int a, int b) { return a > b ? a : b; }

__device__ __forceinline__ u16 f2bf(float x) {
  u32 u = __float_as_uint(x);
  u32 r = (u + 0x7fffu + ((u >> 16) & 1u)) >> 16;
  return (u16)r;
}
__device__ __forceinline__ u32 packbf(float a, float b) {
  return (u32)f2bf(a) | ((u32)f2bf(b) << 16);
}

// ---------------- prep: f32 -> bf16 (optionally scaled) ----------------
__global__ void lf_conv_bf(const float* __restrict__ src, u16* __restrict__ dst,
                           int n, float scale) {
  int i = (blockIdx.x * 256 + threadIdx.x) * 4;
  if (i + 3 >= n + 4 && i >= n) return;
  if (i + 3 < n) {
    float4 v = *(const float4*)(src + i);
    ushort4 o;
    o.x = f2bf(v.x * scale); o.y = f2bf(v.y * scale);
    o.z = f2bf(v.z * scale); o.w = f2bf(v.w * scale);
    *(ushort4*)(dst + i) = o;
  }
}

// ---------------- prep: V [h][s][d] f32 -> Vt [h][d][s] bf16 ----------------
__global__ void lf_transpose_v(const float* __restrict__ v, u16* __restrict__ vt) {
  __shared__ float t[64][65];
  int bid = blockIdx.x;
  int h = bid >> 6;
  int s0 = (bid & 63) << 6;
  int tid = threadIdx.x;
  int r = tid >> 2, c0 = (tid & 3) << 4;
  const float* src = v + ((size_t)h * SLEN + s0 + r) * DH + c0;
#pragma unroll
  for (int j = 0; j < 16; j += 4) {
    float4 a = *(const float4*)(src + j);
    t[r][c0 + j]     = a.x;
    t[r][c0 + j + 1] = a.y;
    t[r][c0 + j + 2] = a.z;
    t[r][c0 + j + 3] = a.w;
  }
  __syncthreads();
  int d = tid >> 2, j0 = (tid & 3) << 4;
  u16 tmp[16];
#pragma unroll
  for (int j = 0; j < 16; ++j) tmp[j] = f2bf(t[j0 + j][d]);
  u16* dst = vt + ((size_t)h * DH + d) * SLEN + s0 + j0;
  ((uint4*)dst)[0] = ((uint4*)tmp)[0];
  ((uint4*)dst)[1] = ((uint4*)tmp)[1];
}

// ---------------- prep: gpos, gmsk, msk, cleanmap ----------------
__global__ void lf_prep_meta(const int* __restrict__ gmask, const int* __restrict__ pmask,
                             const int* __restrict__ nGp,
                             int* __restrict__ gpos, unsigned char* __restrict__ gmsk,
                             unsigned char* __restrict__ msk, unsigned char* __restrict__ cleanmap) {
  const int tid = threadIdx.x;
  const int G = imin(nGp[0], GMAX);
  // phase A: per-key mask bytes (bit0 = pad ok, bit1 = is_global)
  for (int s = tid; s < SLEN; s += 256) {
    unsigned char b = (unsigned char)((pmask[s] ? 1 : 0) | (gmask[s] ? 2 : 0));
    msk[s] = b;
  }
  for (int s = SLEN + tid; s < SLEN + 64; s += 256) msk[s] = 0;
  __syncthreads();
  // phase B: wave 0 builds gpos (globals in order, then non-globals fill)
  if (tid < 64) {
    int lane = tid;
    if (lane < GMAX) gmsk[lane] = 0;
    int cnt = 0;
    for (int c = 0; c < SLEN / 64 && cnt < G; ++c) {
      int s = c * 64 + lane;
      bool isg = gmask[s] != 0;
      u64 b = __ballot(isg);
      int rank = cnt + (int)__popcll(b & ((1ull << lane) - 1ull));
      if (isg && rank < G) gpos[rank] = s;
      cnt += (int)__popcll(b);
    }
    if (cnt < G) {
      int fill = cnt;
      for (int c = 0; c < SLEN / 64 && fill < G; ++c) {
        int s = c * 64 + lane;
        bool non = gmask[s] == 0;
        u64 b = __ballot(non);
        int rank = fill + (int)__popcll(b & ((1ull << lane) - 1ull));
        if (non && rank < G) gpos[rank] = s;
        fill += (int)__popcll(b);
      }
    }
  }
  __syncthreads();
  if (tid < 64) {
    if (tid < G) {
      int p = gpos[tid];
      gmsk[tid] = (unsigned char)(pmask[p] ? 1 : 0);
      msk[p] = (unsigned char)(msk[p] | 4);   // bit2: row overwritten by global path
    }
  } else if (tid >= 128) {
    int c = tid - 128;
    if (c < SLEN / 32) {
      unsigned char ok1 = 1, ok2 = 1;
      for (int k = 0; k < 32; ++k) {
        unsigned char b = msk[c * 32 + k];
        ok1 &= (unsigned char)(((b & 3) == 1) ? 1 : 0);
        ok2 &= (unsigned char)(b & 1);
      }
      cleanmap[c] = (unsigned char)(ok1 | (ok2 << 1));
    }
  }
}

// ---------------- prep: gather global K/Q rows and Vt cols ----------------
__global__ void lf_gather(const u16* __restrict__ qB, const u16* __restrict__ kB,
                          const u16* __restrict__ vtB, const int* __restrict__ gpos,
                          const int* __restrict__ nGp,
                          u16* __restrict__ gq, u16* __restrict__ gk, u16* __restrict__ gvt) {
  const int G = imin(nGp[0], GMAX);
  int idx = blockIdx.x * 256 + threadIdx.x;   // NH*GMAX*DH = 65536
  int h = idx >> 12, g = (idx >> 6) & 63, d = idx & 63;
  size_t oq = ((size_t)h * GMAX + g) * DH + d;
  size_t ot = ((size_t)h * DH + d) * GMAX + g;
  if (g < G) {
    int p = gpos[g];
    gq[oq]  = qB[((size_t)h * SLEN + p) * DH + d];
    gk[oq]  = kB[((size_t)h * SLEN + p) * DH + d];
    gvt[ot] = vtB[((size_t)h * DH + d) * SLEN + p];
  } else {
    gq[oq] = 0; gk[oq] = 0; gvt[ot] = 0;
  }
}

// ---------------- main fused attention ----------------
__global__ __launch_bounds__(256) void lf_attn(
    const u16* __restrict__ qB, const u16* __restrict__ kB, const u16* __restrict__ vtB,
    const u16* __restrict__ gkB, const u16* __restrict__ gqB, const u16* __restrict__ gvtB,
    const int* __restrict__ gpos, const unsigned char* __restrict__ gmskA,
    const unsigned char* __restrict__ mskA, const unsigned char* __restrict__ cleanA,
    const int* __restrict__ nGp, float* __restrict__ out) {
  __shared__ __align__(16) u32 sP[4][256];          // per-wave P tile: [16q][32k] bf16
  __shared__ __align__(16) float sAcc[4][16][64];   // global-path merge
  __shared__ float sM[4][16];
  __shared__ float sL[4][16];

  const int tid  = threadIdx.x;
  const int wv   = tid >> 6;
  const int lane = tid & 63;
  const int ql   = lane & 15;
  const int g    = lane >> 4;
  const int G    = imin(nGp[0], GMAX);
  const float NEGV = -1e30f;

  f32x4 acc[4];
#pragma unroll
  for (int i = 0; i < 4; ++i) acc[i] = (f32x4){0.f, 0.f, 0.f, 0.f};
  float m_run = -1e30f, l_run = 0.f;

  u32* pRow = &sP[wv][ql * 16];
  const bf16x8* pFragPtr = (const bf16x8*)&sP[wv][ql * 16 + g * 4];

  bf16x8 qf0, qf1;

  // S^T = mfma(A=K rows, B=Q^T) over D=64 (two K=32 steps), 2 key tiles of 16
  auto SCORES = [&](const u16* krow, int kb, f32x4& sc0, f32x4& sc1) {
    bf16x8 a;
    a = *(const bf16x8*)(krow + (size_t)(kb + ql) * DH + g * 8);          sc0 = MFMA16(a, qf0, sc0);
    a = *(const bf16x8*)(krow + (size_t)(kb + ql) * DH + 32 + g * 8);     sc0 = MFMA16(a, qf1, sc0);
    a = *(const bf16x8*)(krow + (size_t)(kb + 16 + ql) * DH + g * 8);     sc1 = MFMA16(a, qf0, sc1);
    a = *(const bf16x8*)(krow + (size_t)(kb + 16 + ql) * DH + 32 + g * 8);sc1 = MFMA16(a, qf1, sc1);
  };

  // online-softmax update + PV accumulate (scores in exp2 domain)
  auto SMPV = [&](float (&s)[8], const u16* vrow, int vstride, int kb) {
    float cm = fmaxf(fmaxf(fmaxf(s[0], s[1]), fmaxf(s[2], s[3])),
                     fmaxf(fmaxf(s[4], s[5]), fmaxf(s[6], s[7])));
    cm = fmaxf(cm, __shfl_xor(cm, 16));
    cm = fmaxf(cm, __shfl_xor(cm, 32));
    float mn = fmaxf(m_run, cm);
    float fs = exp2f(m_run - mn);
    float p[8];
    float sum = 0.f;
#pragma unroll
    for (int i = 0; i < 8; ++i) { p[i] = exp2f(s[i] - mn); sum += p[i]; }
    sum += __shfl_xor(sum, 16);
    sum += __shfl_xor(sum, 32);
    l_run = l_run * fs + sum;
    m_run = mn;
#pragma unroll
    for (int i = 0; i < 4; ++i) acc[i] *= fs;
    // P^T tile to LDS: [16q][32k] bf16, lane owns keys 16t+4g+{0..3}
    pRow[2 * g + 0]     = packbf(p[0], p[1]);
    pRow[2 * g + 1]     = packbf(p[2], p[3]);
    pRow[8 + 2 * g + 0] = packbf(p[4], p[5]);
    pRow[8 + 2 * g + 1] = packbf(p[6], p[7]);
    asm volatile("" ::: "memory");      // keep read after cross-lane LDS writes
    bf16x8 pf = *pFragPtr;              // B-frag: keys 8g..8g+7, query ql
#pragma unroll
    for (int dt = 0; dt < 4; ++dt) {
      bf16x8 vf = *(const bf16x8*)(vrow + (size_t)(dt * 16 + ql) * vstride + kb + 8 * g);
      acc[dt] = MFMA16(vf, pf, acc[dt]);
    }
  };

  const int NLOCAL = NH * (SLEN / 64);
  if ((int)blockIdx.x < NLOCAL) {
    // ----- local (band + global-key) path: wave handles 16 queries -----
    const int h  = blockIdx.x >> 6;
    const int s0 = ((blockIdx.x & 63) << 6) + (wv << 4);
    const int sq = s0 + ql;
    const unsigned char mq = mskA[sq];
    const bool skip = (mq & 4) != 0;                 // row owned by global path
    if (__ballot(skip) == ~0ull) return;             // whole wave overwritten

    const u16* kRow  = kB  + (size_t)h * SLEN * DH;
    const u16* vtRow = vtB + (size_t)h * DH * SLEN;
    const u16* qRow  = qB  + ((size_t)h * SLEN + sq) * DH;
    qf0 = *(const bf16x8*)(qRow + g * 8);
    qf1 = *(const bf16x8*)(qRow + 32 + g * 8);

    // global-key chunks
    const u16* gkRow = gkB  + (size_t)h * GMAX * DH;
    const u16* gvRow = gvtB + (size_t)h * DH * GMAX;
    int nGc = (G + 31) >> 5;
    for (int gc = 0; gc < nGc; ++gc) {
      int kb = gc * 32;
      f32x4 sc0 = (f32x4){0.f,0.f,0.f,0.f}, sc1 = sc0;
      SCORES(gkRow, kb, sc0, sc1);
      u32 mw0 = *(const u32*)(gmskA + kb + 4 * g);
      u32 mw1 = *(const u32*)(gmskA + kb + 16 + 4 * g);
      float s[8];
#pragma unroll
      for (int i = 0; i < 4; ++i) {
        s[i]     = ((mw0 >> (8 * i)) & 1) ? sc0[i] : NEGV;
        s[4 + i] = ((mw1 >> (8 * i)) & 1) ? sc1[i] : NEGV;
      }
      SMPV(s, gvRow, GMAX, kb);
    }

    // banded window chunks
    int start = imax(0, s0 - WW) & ~31;
    int hi = imin(SLEN - 1, s0 + 15 + WW);
    for (int kb = start; kb <= hi; kb += 32) {
      f32x4 sc0 = (f32x4){0.f,0.f,0.f,0.f}, sc1 = sc0;
      SCORES(kRow, kb, sc0, sc1);
      bool clean = ((cleanA[kb >> 5] & 1) != 0) && (kb >= s0 + 15 - WW) && (kb + 31 <= s0 + WW);
      float s[8];
      if (clean) {
#pragma unroll
        for (int i = 0; i < 4; ++i) { s[i] = sc0[i]; s[4 + i] = sc1[i]; }
      } else {
        u32 mw0 = *(const u32*)(mskA + kb + 4 * g);
        u32 mw1 = *(const u32*)(mskA + kb + 16 + 4 * g);
#pragma unroll
        for (int i = 0; i < 4; ++i) {
          int k0 = kb + 4 * g + i;
          int k1 = k0 + 16;
          bool v0 = (((mw0 >> (8 * i)) & 3) == 1) && (k0 >= sq - WW) && (k0 <= sq + WW);
          bool v1 = (((mw1 >> (8 * i)) & 3) == 1) && (k1 >= sq - WW) && (k1 <= sq + WW);
          s[i]     = v0 ? sc0[i] : NEGV;
          s[4 + i] = v1 ? sc1[i] : NEGV;
        }
      }
      SMPV(s, vtRow, SLEN, kb);
    }

    float inv = 1.f / l_run;
    if (!skip) {
      float* orow = out + ((size_t)h * SLEN + sq) * DH;
#pragma unroll
      for (int dt = 0; dt < 4; ++dt) {
        f32x4 o = acc[dt] * inv;
        *(f32x4*)(orow + dt * 16 + 4 * g) = o;
      }
    }
    return;
  }

  // ----- global-rows path: full attention, 4 waves split the key range -----
  const int bidl = (int)blockIdx.x - NLOCAL;
  const int h   = bidl >> 2;
  const int gq0 = (bidl & 3) << 4;
  if (gq0 >= G) return;

  const u16* qRow = gqB + ((size_t)h * GMAX + gq0 + ql) * DH;
  qf0 = *(const bf16x8*)(qRow + g * 8);
  qf1 = *(const bf16x8*)(qRow + 32 + g * 8);
  const u16* kRow  = kB  + (size_t)h * SLEN * DH;
  const u16* vtRow = vtB + (size_t)h * DH * SLEN;

  for (int c = 0; c < 32; ++c) {
    int kb = (wv << 10) + (c << 5);
    f32x4 sc0 = (f32x4){0.f,0.f,0.f,0.f}, sc1 = sc0;
    SCORES(kRow, kb, sc0, sc1);
    float s[8];
    if (cleanA[kb >> 5] & 2) {
#pragma unroll
      for (int i = 0; i < 4; ++i) { s[i] = sc0[i]; s[4 + i] = sc1[i]; }
    } else {
      u32 mw0 = *(const u32*)(mskA + kb + 4 * g);
      u32 mw1 = *(const u32*)(mskA + kb + 16 + 4 * g);
#pragma unroll
      for (int i = 0; i < 4; ++i) {
        s[i]     = ((mw0 >> (8 * i)) & 1) ? sc0[i] : NEGV;
        s[4 + i] = ((mw1 >> (8 * i)) & 1) ? sc1[i] : NEGV;
      }
    }
    SMPV(s, vtRow, SLEN, kb);
  }

  // merge 4 wave-partials
  if (g == 0) { sM[wv][ql] = m_run; sL[wv][ql] = l_run; }
#pragma unroll
  for (int dt = 0; dt < 4; ++dt)
    *(f32x4*)&sAcc[wv][ql][dt * 16 + 4 * g] = acc[dt];
  __syncthreads();
#pragma unroll
  for (int ii = 0; ii < 4; ++ii) {
    int idx = tid + ii * 256;
    int qq = idx >> 6, dd = idx & 63;
    float m0 = sM[0][qq], m1 = sM[1][qq], m2 = sM[2][qq], m3 = sM[3][qq];
    float M = fmaxf(fmaxf(m0, m1), fmaxf(m2, m3));
    float e0 = exp2f(m0 - M), e1 = exp2f(m1 - M), e2 = exp2f(m2 - M), e3 = exp2f(m3 - M);
    float L = sL[0][qq] * e0 + sL[1][qq] * e1 + sL[2][qq] * e2 + sL[3][qq] * e3;
    float val = sAcc[0][qq][dd] * e0 + sAcc[1][qq][dd] * e1 +
                sAcc[2][qq][dd] * e2 + sAcc[3][qq][dd] * e3;
    if (gq0 + qq < G) {
      out[((size_t)h * SLEN + gpos[gq0 + qq]) * DH + dd] = val / L;
    }
  }
}

// ---------------- launch ----------------
extern "C" void kernel_launch(void* const* d_in, const int* in_sizes, int n_in,
                              void* d_out, int out_size, void* d_ws, size_t ws_size,
                              hipStream_t stream) {
  const float* q = (const float*)d_in[0];
  const float* k = (const float*)d_in[1];
  const float* v = (const float*)d_in[2];
  const int* gmask = (const int*)d_in[3];
  const int* pmask = (const int*)d_in[4];
  const int* nGp = (const int*)d_in[5];
  float* out = (float*)d_out;
  char* ws = (char*)d_ws;

  constexpr size_t NEL = (size_t)NH * SLEN * DH;            // 4194304
  constexpr size_t OFF_QBF  = 0;
  constexpr size_t OFF_KBF  = OFF_QBF + NEL * 2;
  constexpr size_t OFF_VTBF = OFF_KBF + NEL * 2;
  constexpr size_t OFF_GK   = OFF_VTBF + NEL * 2 + 256;
  constexpr size_t OFF_GQ   = OFF_GK + (size_t)NH * GMAX * DH * 2;
  constexpr size_t OFF_GVT  = OFF_GQ + (size_t)NH * GMAX * DH * 2;
  constexpr size_t OFF_GPOS = OFF_GVT + (size_t)NH * DH * GMAX * 2;
  constexpr size_t OFF_GMSK = OFF_GPOS + 256;
  constexpr size_t OFF_MSK  = OFF_GMSK + 64;
  constexpr size_t OFF_CLEAN = OFF_MSK + SLEN + 64;

  u16* qB  = (u16*)(ws + OFF_QBF);
  u16* kB  = (u16*)(ws + OFF_KBF);
  u16* vtB = (u16*)(ws + OFF_VTBF);
  u16* gk  = (u16*)(ws + OFF_GK);
  u16* gq  = (u16*)(ws + OFF_GQ);
  u16* gvt = (u16*)(ws + OFF_GVT);
  int* gpos = (int*)(ws + OFF_GPOS);
  unsigned char* gmsk = (unsigned char*)(ws + OFF_GMSK);
  unsigned char* msk  = (unsigned char*)(ws + OFF_MSK);
  unsigned char* clean = (unsigned char*)(ws + OFF_CLEAN);

  const float qscale = 0.125f * 1.4426950408889634f;  // 1/sqrt(64) * log2(e)

  lf_conv_bf<<<(int)(NEL / 1024), 256, 0, stream>>>(q, qB, (int)NEL, qscale);
  lf_conv_bf<<<(int)(NEL / 1024), 256, 0, stream>>>(k, kB, (int)NEL, 1.0f);
  lf_transpose_v<<<NH * (SLEN / 64), 256, 0, stream>>>(v, vtB);
  lf_prep_meta<<<1, 256, 0, stream>>>(gmask, pmask, nGp, gpos, gmsk, msk, clean);
  lf_gather<<<NH * GMAX * DH / 256, 256, 0, stream>>>(qB, kB, vtB, gpos, nGp, gq, gk, gvt);

  int nblocks = NH * (SLEN / 64) + NH * (GMAX / 16);
  lf_attn<<<nblocks, 256, 0, stream>>>(qB, kB, vtB, gk, gq, gvt, gpos, gmsk, msk, clean, nGp, out);
}

// Round 2
// 127.794 us; speedup vs baseline: 1.0641x; 1.0641x over previous
//
#include <hip/hip_runtime.h>
#include <hip/hip_bf16.h>

#define SLEN 4096
#define NH   16
#define DH   64
#define WW   256
#define GMAX 64

typedef unsigned short u16;
typedef unsigned int   u32;
typedef unsigned long long u64;
typedef __attribute__((ext_vector_type(8))) short bf16x8;
typedef __attribute__((ext_vector_type(4))) float f32x4;

#define MFMA16(a,b,c) __builtin_amdgcn_mfma_f32_16x16x32_bf16((a),(b),(c),0,0,0)

static __device__ __forceinline__ int imin(int a, int b) { return a < b ? a : b; }
static __device__ __forceinline__ int imax(int a, int b) { return a > b ? a : b; }

__device__ __forceinline__ u16 f2bf(float x) {
  u32 u = __float_as_uint(x);
  u32 r = (u + 0x7fffu + ((u >> 16) & 1u)) >> 16;
  return (u16)r;
}
__device__ __forceinline__ u32 packbf(float a, float b) {
  return (u32)f2bf(a) | ((u32)f2bf(b) << 16);
}

// ---------------- prep: f32 -> bf16 (optionally scaled) ----------------
__global__ void lf_conv_bf(const float* __restrict__ src, u16* __restrict__ dst,
                           int n, float scale) {
  int i = (blockIdx.x * 256 + threadIdx.x) * 4;
  if (i + 3 < n) {
    float4 v = *(const float4*)(src + i);
    ushort4 o;
    o.x = f2bf(v.x * scale); o.y = f2bf(v.y * scale);
    o.z = f2bf(v.z * scale); o.w = f2bf(v.w * scale);
    *(ushort4*)(dst + i) = o;
  }
}

// ---------------- prep: V [h][s][d] f32 -> Vt [h][d][s] bf16 ----------------
__global__ void lf_transpose_v(const float* __restrict__ v, u16* __restrict__ vt) {
  __shared__ float t[64][65];
  int bid = blockIdx.x;
  int h = bid >> 6;
  int s0 = (bid & 63) << 6;
  int tid = threadIdx.x;
  int r = tid >> 2, c0 = (tid & 3) << 4;
  const float* src = v + ((size_t)h * SLEN + s0 + r) * DH + c0;
#pragma unroll
  for (int j = 0; j < 16; j += 4) {
    float4 a = *(const float4*)(src + j);
    t[r][c0 + j]     = a.x;
    t[r][c0 + j + 1] = a.y;
    t[r][c0 + j + 2] = a.z;
    t[r][c0 + j + 3] = a.w;
  }
  __syncthreads();
  int d = tid >> 2, j0 = (tid & 3) << 4;
  u16 tmp[16];
#pragma unroll
  for (int j = 0; j < 16; ++j) tmp[j] = f2bf(t[j0 + j][d]);
  u16* dst = vt + ((size_t)h * DH + d) * SLEN + s0 + j0;
  ((uint4*)dst)[0] = ((uint4*)tmp)[0];
  ((uint4*)dst)[1] = ((uint4*)tmp)[1];
}

// ---------------- prep: gpos, gmsk, msk, cleanmap ----------------
__global__ void lf_prep_meta(const int* __restrict__ gmask, const int* __restrict__ pmask,
                             const int* __restrict__ nGp,
                             int* __restrict__ gpos, unsigned char* __restrict__ gmsk,
                             unsigned char* __restrict__ msk, unsigned char* __restrict__ cleanmap) {
  const int tid = threadIdx.x;
  const int G = imin(nGp[0], GMAX);
  for (int s = tid; s < SLEN; s += 256) {
    unsigned char b = (unsigned char)((pmask[s] ? 1 : 0) | (gmask[s] ? 2 : 0));
    msk[s] = b;
  }
  for (int s = SLEN + tid; s < SLEN + 64; s += 256) msk[s] = 0;
  __syncthreads();
  if (tid < 64) {
    int lane = tid;
    if (lane < GMAX) gmsk[lane] = 0;
    int cnt = 0;
    for (int c = 0; c < SLEN / 64 && cnt < G; ++c) {
      int s = c * 64 + lane;
      bool isg = gmask[s] != 0;
      u64 b = __ballot(isg);
      int rank = cnt + (int)__popcll(b & ((1ull << lane) - 1ull));
      if (isg && rank < G) gpos[rank] = s;
      cnt += (int)__popcll(b);
    }
    if (cnt < G) {
      int fill = cnt;
      for (int c = 0; c < SLEN / 64 && fill < G; ++c) {
        int s = c * 64 + lane;
        bool non = gmask[s] == 0;
        u64 b = __ballot(non);
        int rank = fill + (int)__popcll(b & ((1ull << lane) - 1ull));
        if (non && rank < G) gpos[rank] = s;
        fill += (int)__popcll(b);
      }
    }
  }
  __syncthreads();
  if (tid < 64) {
    if (tid < G) {
      int p = gpos[tid];
      gmsk[tid] = (unsigned char)(pmask[p] ? 1 : 0);
      msk[p] = (unsigned char)(msk[p] | 4);
    }
  } else if (tid >= 128) {
    int c = tid - 128;
    if (c < SLEN / 32) {
      unsigned char ok1 = 1, ok2 = 1;
      for (int k = 0; k < 32; ++k) {
        unsigned char b = msk[c * 32 + k];
        ok1 &= (unsigned char)(((b & 3) == 1) ? 1 : 0);
        ok2 &= (unsigned char)(b & 1);
      }
      cleanmap[c] = (unsigned char)(ok1 | (ok2 << 1));
    }
  }
}

// ---------------- prep: gather global K/Q rows and Vt cols ----------------
__global__ void lf_gather(const u16* __restrict__ qB, const u16* __restrict__ kB,
                          const u16* __restrict__ vtB, const int* __restrict__ gpos,
                          const int* __restrict__ nGp,
                          u16* __restrict__ gq, u16* __restrict__ gk, u16* __restrict__ gvt) {
  const int G = imin(nGp[0], GMAX);
  int idx = blockIdx.x * 256 + threadIdx.x;
  int h = idx >> 12, g = (idx >> 6) & 63, d = idx & 63;
  size_t oq = ((size_t)h * GMAX + g) * DH + d;
  size_t ot = ((size_t)h * DH + d) * GMAX + g;
  if (g < G) {
    int p = gpos[g];
    gq[oq]  = qB[((size_t)h * SLEN + p) * DH + d];
    gk[oq]  = kB[((size_t)h * SLEN + p) * DH + d];
    gvt[ot] = vtB[((size_t)h * DH + d) * SLEN + p];
  } else {
    gq[oq] = 0; gk[oq] = 0; gvt[ot] = 0;
  }
}

// ---------------- main fused attention ----------------
// Grid: 2112 blocks of 256 threads.
//   wg = XCD-swizzled work id; wg%33==0 -> global-rows block (64), else local (2048).
//   Local block: 32 queries; 4 waves = (qw in {0,1}) x (ks in {0,1} key split).
//   Fixed-max softmax (MEXP): no running max, merge = plain sum.
__global__ __launch_bounds__(256) void lf_attn(
    const u16* __restrict__ qB, const u16* __restrict__ kB, const u16* __restrict__ vtB,
    const u16* __restrict__ gkB, const u16* __restrict__ gqB, const u16* __restrict__ gvtB,
    const int* __restrict__ gpos, const unsigned char* __restrict__ gmskA,
    const unsigned char* __restrict__ mskA, const unsigned char* __restrict__ cleanA,
    const int* __restrict__ nGp, float* __restrict__ out) {
  __shared__ __align__(16) u32 sP[4][16 * 36];       // per-wave P tile: 16 rows x 32 u32 (+4 pad)
  __shared__ __align__(16) float sMrg[3][16][68];    // partial-acc merge (padded stride)
  __shared__ float sLm[3][16];

  const int tid  = threadIdx.x;
  const int wv   = tid >> 6;
  const int lane = tid & 63;
  const int ql   = lane & 15;
  const int g    = lane >> 4;
  const float NEGV = -1e30f;
  const float MEXP = 24.0f;

  const int wg = ((int)blockIdx.x & 7) * 264 + ((int)blockIdx.x >> 3);
  const bool gblk = (wg % 33) == 0;
  const int G = imin(nGp[0], GMAX);

  f32x4 acc[4];
#pragma unroll
  for (int i = 0; i < 4; ++i) acc[i] = (f32x4){0.f, 0.f, 0.f, 0.f};
  float lsum = 0.f;

  u32* pRow = &sP[wv][ql * 36];
  bf16x8 qf0, qf1;

  // scores for 64 keys: sc[t] covers keys kb+16t .. kb+16t+15 (lane owns rows 4g+i, col=ql)
  auto SCORE4 = [&](const u16* base, int kb, f32x4 (&sc)[4]) {
#pragma unroll
    for (int t = 0; t < 4; ++t) {
      bf16x8 a0 = *(const bf16x8*)(base + (size_t)(kb + 16 * t + ql) * DH + 8 * g);
      bf16x8 a1 = *(const bf16x8*)(base + (size_t)(kb + 16 * t + ql) * DH + 32 + 8 * g);
      sc[t] = MFMA16(a0, qf0, sc[t]);
      sc[t] = MFMA16(a1, qf1, sc[t]);
    }
  };
  // p -> bf16 P-tile in LDS (rows = q, cols = key/2), b64 stores, then PV (2 k-steps)
  auto PSTORE = [&](const float (&p)[16]) {
    asm volatile("" ::: "memory");
#pragma unroll
    for (int t = 0; t < 4; ++t) {
      uint2 w;
      w.x = packbf(p[4 * t + 0], p[4 * t + 1]);
      w.y = packbf(p[4 * t + 2], p[4 * t + 3]);
      *(uint2*)&pRow[8 * t + 2 * g] = w;
    }
    asm volatile("" ::: "memory");
  };
  auto PVACC = [&](const u16* vbase, int vstride, int kb) {
#pragma unroll
    for (int k2 = 0; k2 < 2; ++k2) {
      bf16x8 pf = *(const bf16x8*)(pRow + 16 * k2 + 4 * g);
#pragma unroll
      for (int dt = 0; dt < 4; ++dt) {
        bf16x8 vf = *(const bf16x8*)(vbase + (size_t)(dt * 16 + ql) * vstride + kb + 32 * k2 + 8 * g);
        acc[dt] = MFMA16(vf, pf, acc[dt]);
      }
    }
    asm volatile("" ::: "memory");
  };

  if (!gblk) {
    // ---------- local path ----------
    const int lid = wg - wg / 33 - 1;          // 0..2047
    const int h   = lid >> 7;
    const int s0  = (lid & 127) << 5;          // block query start (32 queries)
    const int qw  = wv >> 1;
    const int ks  = wv & 1;
    const int s0w = s0 + qw * 16;
    const int sq  = s0w + ql;

    const u16* kRow  = kB  + (size_t)h * SLEN * DH;
    const u16* vtRow = vtB + (size_t)h * DH * SLEN;
    const u16* qRow  = qB  + ((size_t)h * SLEN + sq) * DH;
    qf0 = *(const bf16x8*)(qRow + 8 * g);
    qf1 = *(const bf16x8*)(qRow + 32 + 8 * g);

    if (ks == 0) {
      // global-key chunk (64 slots)
      f32x4 sc[4];
#pragma unroll
      for (int t = 0; t < 4; ++t) sc[t] = (f32x4){0.f, 0.f, 0.f, 0.f};
      SCORE4(gkB + (size_t)h * GMAX * DH, 0, sc);
      float p[16];
#pragma unroll
      for (int t = 0; t < 4; ++t) {
        u32 mw = *(const u32*)(gmskA + 16 * t + 4 * g);
#pragma unroll
        for (int i = 0; i < 4; ++i) {
          float s = ((mw >> (8 * i)) & 1) ? sc[t][i] : NEGV;
          p[4 * t + i] = __builtin_amdgcn_exp2f(s - MEXP);
          lsum += p[4 * t + i];
        }
      }
      PSTORE(p);
      PVACC(gvtB + (size_t)h * DH * GMAX, GMAX, 0);
    }

    // band chunks of 64 keys, interleaved between the two ks waves
    const int start = imax(0, s0 - WW) & ~63;
    const int kbend = imin(SLEN - 1, s0 + 31 + WW);
    for (int kb = start + (ks ? 0 : 64); kb <= kbend; kb += 128) {
      f32x4 sc[4];
#pragma unroll
      for (int t = 0; t < 4; ++t) sc[t] = (f32x4){0.f, 0.f, 0.f, 0.f};
      SCORE4(kRow, kb, sc);
      bool cl = ((cleanA[kb >> 5] & cleanA[(kb >> 5) + 1] & 1) != 0) &&
                (kb >= s0w + 15 - WW) && (kb + 63 <= s0w + WW);
      float p[16];
      if (cl) {
#pragma unroll
        for (int t = 0; t < 4; ++t)
#pragma unroll
          for (int i = 0; i < 4; ++i) {
            p[4 * t + i] = __builtin_amdgcn_exp2f(sc[t][i] - MEXP);
            lsum += p[4 * t + i];
          }
      } else {
#pragma unroll
        for (int t = 0; t < 4; ++t) {
          u32 mw = *(const u32*)(mskA + kb + 16 * t + 4 * g);
#pragma unroll
          for (int i = 0; i < 4; ++i) {
            int k = kb + 16 * t + 4 * g + i;
            bool v = (((mw >> (8 * i)) & 3) == 1) && (k >= sq - WW) && (k <= sq + WW);
            float s = v ? sc[t][i] : NEGV;
            p[4 * t + i] = __builtin_amdgcn_exp2f(s - MEXP);
            lsum += p[4 * t + i];
          }
        }
      }
      PSTORE(p);
      PVACC(vtRow, SLEN, kb);
    }

    // reduce l across the 4 key-groups of the wave
    lsum += __shfl_xor(lsum, 16);
    lsum += __shfl_xor(lsum, 32);

    // merge the two ks waves
    if (ks == 1) {
#pragma unroll
      for (int dt = 0; dt < 4; ++dt)
        *(f32x4*)&sMrg[qw][ql][dt * 16 + 4 * g] = acc[dt];
      if (lane < 16) sLm[qw][lane] = lsum;
    }
    __syncthreads();
    if (ks == 0) {
      lsum += sLm[qw][ql];
      float inv = 1.f / lsum;
      bool skip = (mskA[sq] & 4) != 0;
      if (!skip) {
        float* orow = out + ((size_t)h * SLEN + sq) * DH;
#pragma unroll
        for (int dt = 0; dt < 4; ++dt) {
          f32x4 m = *(const f32x4*)&sMrg[qw][ql][dt * 16 + 4 * g];
          f32x4 o = (acc[dt] + m) * inv;
          *(f32x4*)(orow + dt * 16 + 4 * g) = o;
        }
      }
    }
    return;
  }

  // ---------- global-rows path: full attention over all keys ----------
  const int gb  = wg / 33;
  const int h   = gb >> 2;
  const int gq0 = (gb & 3) << 4;

  const u16* qRow = gqB + ((size_t)h * GMAX + gq0 + ql) * DH;
  qf0 = *(const bf16x8*)(qRow + 8 * g);
  qf1 = *(const bf16x8*)(qRow + 32 + 8 * g);
  const u16* kRow  = kB  + (size_t)h * SLEN * DH;
  const u16* vtRow = vtB + (size_t)h * DH * SLEN;

  for (int c = 0; c < 16; ++c) {
    int kb = (wv << 10) + (c << 6);
    f32x4 sc[4];
#pragma unroll
    for (int t = 0; t < 4; ++t) sc[t] = (f32x4){0.f, 0.f, 0.f, 0.f};
    SCORE4(kRow, kb, sc);
    bool cl = ((cleanA[kb >> 5] & cleanA[(kb >> 5) + 1] & 2) != 0);
    float p[16];
    if (cl) {
#pragma unroll
      for (int t = 0; t < 4; ++t)
#pragma unroll
        for (int i = 0; i < 4; ++i) {
          p[4 * t + i] = __builtin_amdgcn_exp2f(sc[t][i] - MEXP);
          lsum += p[4 * t + i];
        }
    } else {
#pragma unroll
      for (int t = 0; t < 4; ++t) {
        u32 mw = *(const u32*)(mskA + kb + 16 * t + 4 * g);
#pragma unroll
        for (int i = 0; i < 4; ++i) {
          float s = ((mw >> (8 * i)) & 1) ? sc[t][i] : NEGV;
          p[4 * t + i] = __builtin_amdgcn_exp2f(s - MEXP);
          lsum += p[4 * t + i];
        }
      }
    }
    PSTORE(p);
    PVACC(vtRow, SLEN, kb);
  }

  lsum += __shfl_xor(lsum, 16);
  lsum += __shfl_xor(lsum, 32);

  if (wv > 0) {
#pragma unroll
    for (int dt = 0; dt < 4; ++dt)
      *(f32x4*)&sMrg[wv - 1][ql][dt * 16 + 4 * g] = acc[dt];
    if (lane < 16) sLm[wv - 1][lane] = lsum;
  }
  __syncthreads();
  if (wv == 0) {
    lsum += sLm[0][ql] + sLm[1][ql] + sLm[2][ql];
    float inv = 1.f / lsum;
    int qg = gq0 + ql;
    if (qg < G) {
      float* orow = out + ((size_t)h * SLEN + gpos[qg]) * DH;
#pragma unroll
      for (int dt = 0; dt < 4; ++dt) {
        f32x4 m0 = *(const f32x4*)&sMrg[0][ql][dt * 16 + 4 * g];
        f32x4 m1 = *(const f32x4*)&sMrg[1][ql][dt * 16 + 4 * g];
        f32x4 m2 = *(const f32x4*)&sMrg[2][ql][dt * 16 + 4 * g];
        f32x4 o = (acc[dt] + m0 + m1 + m2) * inv;
        *(f32x4*)(orow + dt * 16 + 4 * g) = o;
      }
    }
  }
}

// ---------------- launch ----------------
extern "C" void kernel_launch(void* const* d_in, const int* in_sizes, int n_in,
                              void* d_out, int out_size, void* d_ws, size_t ws_size,
                              hipStream_t stream) {
  const float* q = (const float*)d_in[0];
  const float* k = (const float*)d_in[1];
  const float* v = (const float*)d_in[2];
  const int* gmask = (const int*)d_in[3];
  const int* pmask = (const int*)d_in[4];
  const int* nGp = (const int*)d_in[5];
  float* out = (float*)d_out;
  char* ws = (char*)d_ws;

  constexpr size_t NEL = (size_t)NH * SLEN * DH;
  constexpr size_t OFF_QBF  = 0;
  constexpr size_t OFF_KBF  = OFF_QBF + NEL * 2;
  constexpr size_t OFF_VTBF = OFF_KBF + NEL * 2;
  constexpr size_t OFF_GK   = OFF_VTBF + NEL * 2 + 256;
  constexpr size_t OFF_GQ   = OFF_GK + (size_t)NH * GMAX * DH * 2;
  constexpr size_t OFF_GVT  = OFF_GQ + (size_t)NH * GMAX * DH * 2;
  constexpr size_t OFF_GPOS = OFF_GVT + (size_t)NH * DH * GMAX * 2;
  constexpr size_t OFF_GMSK = OFF_GPOS + 256;
  constexpr size_t OFF_MSK  = OFF_GMSK + 64;
  constexpr size_t OFF_CLEAN = OFF_MSK + SLEN + 64;

  u16* qB  = (u16*)(ws + OFF_QBF);
  u16* kB  = (u16*)(ws + OFF_KBF);
  u16* vtB = (u16*)(ws + OFF_VTBF);
  u16* gk  = (u16*)(ws + OFF_GK);
  u16* gq  = (u16*)(ws + OFF_GQ);
  u16* gvt = (u16*)(ws + OFF_GVT);
  int* gpos = (int*)(ws + OFF_GPOS);
  unsigned char* gmsk = (unsigned char*)(ws + OFF_GMSK);
  unsigned char* msk  = (unsigned char*)(ws + OFF_MSK);
  unsigned char* clean = (unsigned char*)(ws + OFF_CLEAN);

  const float qscale = 0.125f * 1.4426950408889634f;  // 1/sqrt(64) * log2(e)

  lf_conv_bf<<<(int)(NEL / 1024), 256, 0, stream>>>(q, qB, (int)NEL, qscale);
  lf_conv_bf<<<(int)(NEL / 1024), 256, 0, stream>>>(k, kB, (int)NEL, 1.0f);
  lf_transpose_v<<<NH * (SLEN / 64), 256, 0, stream>>>(v, vtB);
  lf_prep_meta<<<1, 256, 0, stream>>>(gmask, pmask, nGp, gpos, gmsk, msk, clean);
  lf_gather<<<NH * GMAX * DH / 256, 256, 0, stream>>>(qB, kB, vtB, gpos, nGp, gq, gk, gvt);

  lf_attn<<<2112, 256, 0, stream>>>(qB, kB, vtB, gk, gq, gvt, gpos, gmsk, msk, clean, nGp, out);
}

// Round 3
// 117.329 us; speedup vs baseline: 1.1590x; 1.0892x over previous
//
#include <hip/hip_runtime.h>
#include <hip/hip_bf16.h>

#define SLEN 4096
#define NH   16
#define DH   64
#define WW   256
#define GMAX 64

typedef unsigned short u16;
typedef unsigned int   u32;
typedef unsigned long long u64;
typedef __attribute__((ext_vector_type(8))) short bf16x8;
typedef __attribute__((ext_vector_type(4))) float f32x4;

#define MFMA16(a,b,c) __builtin_amdgcn_mfma_f32_16x16x32_bf16((a),(b),(c),0,0,0)

static __device__ __forceinline__ int imin(int a, int b) { return a < b ? a : b; }
static __device__ __forceinline__ int imax(int a, int b) { return a > b ? a : b; }

__device__ __forceinline__ u32 cvtpk(float lo, float hi) {
  u32 r;
  asm("v_cvt_pk_bf16_f32 %0, %1, %2" : "=v"(r) : "v"(lo), "v"(hi));
  return r;
}

// ---------------- prep1: fused q/k bf16-convert + V transpose(σ-permuted) + meta ----------------
// grid: [0,2048) q-conv, [2048,4096) k-conv, [4096,5120) v-transpose, 5120 meta
__global__ __launch_bounds__(256) void lf_prep1(
    const float* __restrict__ q, const float* __restrict__ k, const float* __restrict__ v,
    const int* __restrict__ gmask, const int* __restrict__ pmask, const int* __restrict__ nGp,
    u16* __restrict__ qB, u16* __restrict__ kB, u16* __restrict__ vtB,
    int* __restrict__ gpos, unsigned char* __restrict__ gmsk,
    unsigned char* __restrict__ msk, unsigned char* __restrict__ cleanmap, float qscale) {
  const int bid = blockIdx.x;
  const int tid = threadIdx.x;
  if (bid < 4096) {
    const bool isq = bid < 2048;
    const float sc = isq ? qscale : 1.0f;
    const float* src = isq ? q : k;
    u16* dst = isq ? qB : kB;
    int i = ((isq ? bid : bid - 2048) * 256 + tid) * 8;
    float4 v0 = *(const float4*)(src + i);
    float4 v1 = *(const float4*)(src + i + 4);
    uint4 w;
    w.x = cvtpk(v0.x * sc, v0.y * sc);
    w.y = cvtpk(v0.z * sc, v0.w * sc);
    w.z = cvtpk(v1.x * sc, v1.y * sc);
    w.w = cvtpk(v1.z * sc, v1.w * sc);
    *(uint4*)(dst + i) = w;
    return;
  }
  if (bid < 5120) {
    // V [h][s][d] f32 -> Vt2 [h][d][s with sigma-permuted 32-key groups] bf16
    __shared__ float t[64][65];
    int b = bid - 4096;
    int h = b >> 6, s0 = (b & 63) << 6;
    int r = tid >> 2, c0 = (tid & 3) << 4;
    const float* src = v + ((size_t)h * SLEN + s0 + r) * DH + c0;
#pragma unroll
    for (int j = 0; j < 16; j += 4) {
      float4 a = *(const float4*)(src + j);
      t[r][c0 + j]     = a.x;
      t[r][c0 + j + 1] = a.y;
      t[r][c0 + j + 2] = a.z;
      t[r][c0 + j + 3] = a.w;
    }
    __syncthreads();
    int d = tid >> 2, j0 = (tid & 3) << 4;      // j0 in {0,16,32,48}
    int grp  = j0 & 32;                          // 32-key group base
    int half = (j0 & 16) ? 4 : 0;                // keys >=16 of group -> slots +4
    u16* dst = vtB + ((size_t)h * DH + d) * SLEN + s0 + grp;
#pragma unroll
    for (int q4 = 0; q4 < 4; ++q4) {
      uint2 val;
      val.x = cvtpk(t[j0 + 4 * q4 + 0][d], t[j0 + 4 * q4 + 1][d]);
      val.y = cvtpk(t[j0 + 4 * q4 + 2][d], t[j0 + 4 * q4 + 3][d]);
      *(uint2*)(dst + 8 * q4 + half) = val;      // sigma^-1: key 4q4+i -> slot 8q4+half+i
    }
    return;
  }
  // ---- meta block ----
  const int G = imin(nGp[0], GMAX);
  for (int s = tid; s < SLEN; s += 256) {
    unsigned char b = (unsigned char)((pmask[s] ? 1 : 0) | (gmask[s] ? 2 : 0));
    msk[s] = b;
  }
  for (int s = SLEN + tid; s < SLEN + 64; s += 256) msk[s] = 0;
  __syncthreads();
  if (tid < 64) {
    int lane = tid;
    if (lane < GMAX) gmsk[lane] = 0;
    int cnt = 0;
    for (int c = 0; c < SLEN / 64 && cnt < G; ++c) {
      int s = c * 64 + lane;
      bool isg = gmask[s] != 0;
      u64 b = __ballot(isg);
      int rank = cnt + (int)__popcll(b & ((1ull << lane) - 1ull));
      if (isg && rank < G) gpos[rank] = s;
      cnt += (int)__popcll(b);
    }
    if (cnt < G) {
      int fill = cnt;
      for (int c = 0; c < SLEN / 64 && fill < G; ++c) {
        int s = c * 64 + lane;
        bool non = gmask[s] == 0;
        u64 b = __ballot(non);
        int rank = fill + (int)__popcll(b & ((1ull << lane) - 1ull));
        if (non && rank < G) gpos[rank] = s;
        fill += (int)__popcll(b);
      }
    }
  }
  __syncthreads();
  if (tid < 64) {
    if (tid < G) {
      int p = gpos[tid];
      gmsk[tid] = (unsigned char)(pmask[p] ? 1 : 0);
      msk[p] = (unsigned char)(msk[p] | 4);
    }
  } else if (tid >= 128) {
    int c = tid - 128;
    if (c < SLEN / 32) {
      unsigned char ok1 = 1, ok2 = 1;
      for (int kk = 0; kk < 32; ++kk) {
        unsigned char b = msk[c * 32 + kk];
        ok1 &= (unsigned char)(((b & 3) == 1) ? 1 : 0);
        ok2 &= (unsigned char)(b & 1);
      }
      cleanmap[c] = (unsigned char)(ok1 | (ok2 << 1));
    }
  }
}

// ---------------- prep2: gather global K/Q rows and sigma-permuted Vt cols ----------------
__global__ void lf_gather(const u16* __restrict__ qB, const u16* __restrict__ kB,
                          const u16* __restrict__ vtB, const int* __restrict__ gpos,
                          const int* __restrict__ nGp,
                          u16* __restrict__ gq, u16* __restrict__ gk, u16* __restrict__ gvt) {
  const int G = imin(nGp[0], GMAX);
  int idx = blockIdx.x * 256 + threadIdx.x;
  int h = idx >> 12, m = (idx >> 6) & 63, d = idx & 63;
  size_t oq = ((size_t)h * GMAX + m) * DH + d;
  int r = m & 31;
  int pos = ((r & 12) << 1) + ((r & 16) >> 2) + (r & 3);   // sigma^-1 within 32-group
  size_t ot = ((size_t)h * DH + d) * GMAX + (m & 32) + pos;
  if (m < G) {
    int p = gpos[m];
    gq[oq]  = qB[((size_t)h * SLEN + p) * DH + d];
    gk[oq]  = kB[((size_t)h * SLEN + p) * DH + d];
    gvt[ot] = vtB[((size_t)h * DH + d) * SLEN + (p & ~31) +
                  (((p & 12) << 1) + ((p & 16) >> 2) + (p & 3))];
    // note: vtB itself is sigma-permuted; fetch key p from its permuted slot
  } else {
    gq[oq] = 0; gk[oq] = 0; gvt[ot] = 0;
  }
}

// ---------------- main fused attention ----------------
// Grid: 2176 blocks. wg = XCD-swizzled id; wg%17==0 -> global-rows block (128, key-split 2x),
// else local (2048): 32 queries, 4 waves = (qw) x (ks key split). Fixed-max softmax.
// PV path: P stays in-lane (sigma-permuted V), no LDS in the main loop.
__global__ __launch_bounds__(256) void lf_attn(
    const u16* __restrict__ qB, const u16* __restrict__ kB, const u16* __restrict__ vtB,
    const u16* __restrict__ gkB, const u16* __restrict__ gqB, const u16* __restrict__ gvtB,
    const int* __restrict__ gpos, const unsigned char* __restrict__ gmskA,
    const unsigned char* __restrict__ mskA, const unsigned char* __restrict__ cleanA,
    const int* __restrict__ nGp, float* __restrict__ out,
    float* __restrict__ pAcc, float* __restrict__ pL) {
  __shared__ __align__(16) float sMrg[3][16][68];
  __shared__ float sLm[3][16];

  const int tid  = threadIdx.x;
  const int wv   = tid >> 6;
  const int lane = tid & 63;
  const int ql   = lane & 15;
  const int g    = lane >> 4;
  const float NEGV = -1e30f;
  const float MEXP = 24.0f;

  const int wg = ((int)blockIdx.x & 7) * 272 + ((int)blockIdx.x >> 3);
  const bool gblk = (wg % 17) == 0;
  const int G = imin(nGp[0], GMAX);

  f32x4 acc[4];
#pragma unroll
  for (int i = 0; i < 4; ++i) acc[i] = (f32x4){0.f, 0.f, 0.f, 0.f};
  f32x4 lsv = (f32x4){0.f, 0.f, 0.f, 0.f};

  bf16x8 qf0, qf1;

  auto SCORE4 = [&](const u16* base, int kb, f32x4 (&sc)[4]) {
#pragma unroll
    for (int t = 0; t < 4; ++t) {
      bf16x8 a0 = *(const bf16x8*)(base + (size_t)(kb + 16 * t + ql) * DH + 8 * g);
      bf16x8 a1 = *(const bf16x8*)(base + (size_t)(kb + 16 * t + ql) * DH + 32 + 8 * g);
      sc[t] = MFMA16(a0, qf0, sc[t]);
      sc[t] = MFMA16(a1, qf1, sc[t]);
    }
  };
  // PV accumulate: B-frag built in-lane from pv (sigma matches permuted V layout)
  auto PVACC = [&](const u16* vbase, int vstride, int kb, const f32x4 (&pv)[4]) {
#pragma unroll
    for (int s2 = 0; s2 < 2; ++s2) {
      union { u32 w[4]; bf16x8 v8; } u;
      u.w[0] = cvtpk(pv[2 * s2][0], pv[2 * s2][1]);
      u.w[1] = cvtpk(pv[2 * s2][2], pv[2 * s2][3]);
      u.w[2] = cvtpk(pv[2 * s2 + 1][0], pv[2 * s2 + 1][1]);
      u.w[3] = cvtpk(pv[2 * s2 + 1][2], pv[2 * s2 + 1][3]);
#pragma unroll
      for (int dt = 0; dt < 4; ++dt) {
        bf16x8 vf = *(const bf16x8*)(vbase + (size_t)(dt * 16 + ql) * vstride + kb + 32 * s2 + 8 * g);
        acc[dt] = MFMA16(vf, u.v8, acc[dt]);
      }
    }
  };

  if (!gblk) {
    // ---------- local path ----------
    const int lid = wg - wg / 17 - 1;          // 0..2047
    const int h   = lid >> 7;
    const int s0  = (lid & 127) << 5;
    const int qw  = wv >> 1;
    const int ks  = wv & 1;
    const int s0w = s0 + qw * 16;
    const int sq  = s0w + ql;

    const u16* kRow  = kB  + (size_t)h * SLEN * DH;
    const u16* vtRow = vtB + (size_t)h * DH * SLEN;
    const u16* qRow  = qB  + ((size_t)h * SLEN + sq) * DH;
    qf0 = *(const bf16x8*)(qRow + 8 * g);
    qf1 = *(const bf16x8*)(qRow + 32 + 8 * g);

    if (ks == 0 && G > 0) {
      f32x4 sc[4];
#pragma unroll
      for (int t = 0; t < 4; ++t) sc[t] = (f32x4){0.f, 0.f, 0.f, 0.f};
      SCORE4(gkB + (size_t)h * GMAX * DH, 0, sc);
      f32x4 pv[4];
#pragma unroll
      for (int t = 0; t < 4; ++t) {
        u32 mw = *(const u32*)(gmskA + 16 * t + 4 * g);
#pragma unroll
        for (int i = 0; i < 4; ++i) {
          float s = ((mw >> (8 * i)) & 1) ? sc[t][i] : NEGV;
          pv[t][i] = __builtin_amdgcn_exp2f(s - MEXP);
        }
      }
      lsv += pv[0] + pv[1] + pv[2] + pv[3];
      PVACC(gvtB + (size_t)h * DH * GMAX, GMAX, 0, pv);
    }

    const int start = imax(0, s0 - WW) & ~63;
    const int kbend = imin(SLEN - 1, s0 + 31 + WW);
    for (int kb = start + (ks ? 0 : 64); kb <= kbend; kb += 128) {
      f32x4 sc[4];
#pragma unroll
      for (int t = 0; t < 4; ++t) sc[t] = (f32x4){0.f, 0.f, 0.f, 0.f};
      SCORE4(kRow, kb, sc);
      bool cl = ((cleanA[kb >> 5] & cleanA[(kb >> 5) + 1] & 1) != 0) &&
                (kb >= s0w + 15 - WW) && (kb + 63 <= s0w + WW);
      f32x4 pv[4];
      if (cl) {
#pragma unroll
        for (int t = 0; t < 4; ++t)
#pragma unroll
          for (int i = 0; i < 4; ++i)
            pv[t][i] = __builtin_amdgcn_exp2f(sc[t][i] - MEXP);
      } else {
#pragma unroll
        for (int t = 0; t < 4; ++t) {
          u32 mw = *(const u32*)(mskA + kb + 16 * t + 4 * g);
#pragma unroll
          for (int i = 0; i < 4; ++i) {
            int kkey = kb + 16 * t + 4 * g + i;
            bool vok = (((mw >> (8 * i)) & 3) == 1) && (kkey >= sq - WW) && (kkey <= sq + WW);
            float s = vok ? sc[t][i] : NEGV;
            pv[t][i] = __builtin_amdgcn_exp2f(s - MEXP);
          }
        }
      }
      lsv += pv[0] + pv[1] + pv[2] + pv[3];
      PVACC(vtRow, SLEN, kb, pv);
    }

    float lsum = lsv[0] + lsv[1] + lsv[2] + lsv[3];
    lsum += __shfl_xor(lsum, 16);
    lsum += __shfl_xor(lsum, 32);

    if (ks == 1) {
#pragma unroll
      for (int dt = 0; dt < 4; ++dt)
        *(f32x4*)&sMrg[qw][ql][dt * 16 + 4 * g] = acc[dt];
      if (lane < 16) sLm[qw][lane] = lsum;
    }
    __syncthreads();
    if (ks == 0) {
      lsum += sLm[qw][ql];
      float inv = 1.f / lsum;
      bool skip = (mskA[sq] & 4) != 0;
      if (!skip) {
        float* orow = out + ((size_t)h * SLEN + sq) * DH;
#pragma unroll
        for (int dt = 0; dt < 4; ++dt) {
          f32x4 m = *(const f32x4*)&sMrg[qw][ql][dt * 16 + 4 * g];
          f32x4 o = (acc[dt] + m) * inv;
          *(f32x4*)(orow + dt * 16 + 4 * g) = o;
        }
      }
    }
    return;
  }

  // ---------- global-rows path: key-split in half, partials to workspace ----------
  const int gb   = wg / 17;                  // 0..127
  const int h    = gb >> 3;
  const int sub  = gb & 7;
  const int gq0  = (sub >> 1) << 4;
  const int half = sub & 1;
  if (gq0 >= G) return;

  const u16* qRow = gqB + ((size_t)h * GMAX + gq0 + ql) * DH;
  qf0 = *(const bf16x8*)(qRow + 8 * g);
  qf1 = *(const bf16x8*)(qRow + 32 + 8 * g);
  const u16* kRow  = kB  + (size_t)h * SLEN * DH;
  const u16* vtRow = vtB + (size_t)h * DH * SLEN;

  for (int c = 0; c < 8; ++c) {
    int kb = half * 2048 + (wv << 9) + (c << 6);
    f32x4 sc[4];
#pragma unroll
    for (int t = 0; t < 4; ++t) sc[t] = (f32x4){0.f, 0.f, 0.f, 0.f};
    SCORE4(kRow, kb, sc);
    bool cl = ((cleanA[kb >> 5] & cleanA[(kb >> 5) + 1] & 2) != 0);
    f32x4 pv[4];
    if (cl) {
#pragma unroll
      for (int t = 0; t < 4; ++t)
#pragma unroll
        for (int i = 0; i < 4; ++i)
          pv[t][i] = __builtin_amdgcn_exp2f(sc[t][i] - MEXP);
    } else {
#pragma unroll
      for (int t = 0; t < 4; ++t) {
        u32 mw = *(const u32*)(mskA + kb + 16 * t + 4 * g);
#pragma unroll
        for (int i = 0; i < 4; ++i) {
          float s = ((mw >> (8 * i)) & 1) ? sc[t][i] : NEGV;
          pv[t][i] = __builtin_amdgcn_exp2f(s - MEXP);
        }
      }
    }
    lsv += pv[0] + pv[1] + pv[2] + pv[3];
    PVACC(vtRow, SLEN, kb, pv);
  }

  float lsum = lsv[0] + lsv[1] + lsv[2] + lsv[3];
  lsum += __shfl_xor(lsum, 16);
  lsum += __shfl_xor(lsum, 32);

  if (wv > 0) {
#pragma unroll
    for (int dt = 0; dt < 4; ++dt)
      *(f32x4*)&sMrg[wv - 1][ql][dt * 16 + 4 * g] = acc[dt];
    if (lane < 16) sLm[wv - 1][lane] = lsum;
  }
  __syncthreads();
  if (wv == 0) {
    lsum += sLm[0][ql] + sLm[1][ql] + sLm[2][ql];
    float* pa = pAcc + ((size_t)gb * 16 + ql) * 64;
#pragma unroll
    for (int dt = 0; dt < 4; ++dt) {
      f32x4 m0 = *(const f32x4*)&sMrg[0][ql][dt * 16 + 4 * g];
      f32x4 m1 = *(const f32x4*)&sMrg[1][ql][dt * 16 + 4 * g];
      f32x4 m2 = *(const f32x4*)&sMrg[2][ql][dt * 16 + 4 * g];
      *(f32x4*)&pa[dt * 16 + 4 * g] = acc[dt] + m0 + m1 + m2;
    }
    if (g == 0) pL[gb * 16 + ql] = lsum;
  }
}

// ---------------- merge the two key-halves of global rows ----------------
__global__ void lf_gmerge(const float* __restrict__ pAcc, const float* __restrict__ pL,
                          const int* __restrict__ gpos, const int* __restrict__ nGp,
                          float* __restrict__ out) {
  const int G = imin(nGp[0], GMAX);
  int b = blockIdx.x;                  // h*4 + gq0i
  int h = b >> 2, gq0 = (b & 3) << 4;
  int t = threadIdx.x;
  int qg = gq0 + (t >> 4);
  int d4 = (t & 15) << 2;
  if (qg >= G) return;
  int q = t >> 4;
  int gb0 = b << 1, gb1 = gb0 + 1;
  float L = pL[gb0 * 16 + q] + pL[gb1 * 16 + q];
  f32x4 a0 = *(const f32x4*)&pAcc[((size_t)gb0 * 16 + q) * 64 + d4];
  f32x4 a1 = *(const f32x4*)&pAcc[((size_t)gb1 * 16 + q) * 64 + d4];
  f32x4 o = (a0 + a1) * (1.f / L);
  *(f32x4*)&out[((size_t)h * SLEN + gpos[qg]) * DH + d4] = o;
}

// ---------------- launch ----------------
extern "C" void kernel_launch(void* const* d_in, const int* in_sizes, int n_in,
                              void* d_out, int out_size, void* d_ws, size_t ws_size,
                              hipStream_t stream) {
  const float* q = (const float*)d_in[0];
  const float* k = (const float*)d_in[1];
  const float* v = (const float*)d_in[2];
  const int* gmask = (const int*)d_in[3];
  const int* pmask = (const int*)d_in[4];
  const int* nGp = (const int*)d_in[5];
  float* out = (float*)d_out;
  char* ws = (char*)d_ws;

  constexpr size_t NEL = (size_t)NH * SLEN * DH;
  constexpr size_t OFF_QBF  = 0;
  constexpr size_t OFF_KBF  = OFF_QBF + NEL * 2;
  constexpr size_t OFF_VTBF = OFF_KBF + NEL * 2;
  constexpr size_t OFF_GK   = OFF_VTBF + NEL * 2 + 256;
  constexpr size_t OFF_GQ   = OFF_GK + (size_t)NH * GMAX * DH * 2;
  constexpr size_t OFF_GVT  = OFF_GQ + (size_t)NH * GMAX * DH * 2;
  constexpr size_t OFF_GPOS = OFF_GVT + (size_t)NH * DH * GMAX * 2;
  constexpr size_t OFF_GMSK = OFF_GPOS + 256;
  constexpr size_t OFF_MSK  = OFF_GMSK + 64;
  constexpr size_t OFF_CLEAN = OFF_MSK + SLEN + 64;
  constexpr size_t OFF_PACC = OFF_CLEAN + 256;
  constexpr size_t OFF_PL   = OFF_PACC + (size_t)128 * 16 * 64 * 4;

  u16* qB  = (u16*)(ws + OFF_QBF);
  u16* kB  = (u16*)(ws + OFF_KBF);
  u16* vtB = (u16*)(ws + OFF_VTBF);
  u16* gk  = (u16*)(ws + OFF_GK);
  u16* gq  = (u16*)(ws + OFF_GQ);
  u16* gvt = (u16*)(ws + OFF_GVT);
  int* gpos = (int*)(ws + OFF_GPOS);
  unsigned char* gmsk = (unsigned char*)(ws + OFF_GMSK);
  unsigned char* msk  = (unsigned char*)(ws + OFF_MSK);
  unsigned char* clean = (unsigned char*)(ws + OFF_CLEAN);
  float* pAcc = (float*)(ws + OFF_PACC);
  float* pL   = (float*)(ws + OFF_PL);

  const float qscale = 0.125f * 1.4426950408889634f;  // 1/sqrt(64) * log2(e)

  lf_prep1<<<5121, 256, 0, stream>>>(q, k, v, gmask, pmask, nGp,
                                     qB, kB, vtB, gpos, gmsk, msk, clean, qscale);
  lf_gather<<<256, 256, 0, stream>>>(qB, kB, vtB, gpos, nGp, gq, gk, gvt);
  lf_attn<<<2176, 256, 0, stream>>>(qB, kB, vtB, gk, gq, gvt, gpos, gmsk, msk, clean,
                                    nGp, out, pAcc, pL);
  lf_gmerge<<<64, 256, 0, stream>>>(pAcc, pL, gpos, nGp, out);
}

// Round 4
// 115.319 us; speedup vs baseline: 1.1792x; 1.0174x over previous
//
#include <hip/hip_runtime.h>
#include <hip/hip_bf16.h>

#define SLEN 4096
#define NH   16
#define DH   64
#define WW   256
#define GMAX 64

typedef unsigned short u16;
typedef unsigned int   u32;
typedef unsigned long long u64;
typedef __attribute__((ext_vector_type(8))) short bf16x8;
typedef __attribute__((ext_vector_type(4))) float f32x4;

#define MFMA16(a,b,c) __builtin_amdgcn_mfma_f32_16x16x32_bf16((a),(b),(c),0,0,0)

static __device__ __forceinline__ int imin(int a, int b) { return a < b ? a : b; }
static __device__ __forceinline__ int imax(int a, int b) { return a > b ? a : b; }

__device__ __forceinline__ u32 cvtpk(float lo, float hi) {
  u32 r;
  asm("v_cvt_pk_bf16_f32 %0, %1, %2" : "=v"(r) : "v"(lo), "v"(hi));
  return r;
}

// ---------------- prep1: fused q/k bf16-convert + V transpose (tiled, σ-permuted) + meta ----
// grid: [0,2048) q-conv, [2048,4096) k-conv, [4096,5120) v-transpose, 5120 meta
// V tile layout: vtB[((h*64 + s/64)*64 + d)*64 + sigma_slot(s%64)]  (one 8KB tile per 64 keys)
__global__ __launch_bounds__(256) void lf_prep1(
    const float* __restrict__ q, const float* __restrict__ k, const float* __restrict__ v,
    const int* __restrict__ gmask, const int* __restrict__ pmask, const int* __restrict__ nGp,
    u16* __restrict__ qB, u16* __restrict__ kB, u16* __restrict__ vtB,
    int* __restrict__ gpos, unsigned char* __restrict__ gmsk,
    unsigned char* __restrict__ msk, unsigned char* __restrict__ cleanmap, float qscale) {
  const int bid = blockIdx.x;
  const int tid = threadIdx.x;
  if (bid < 4096) {
    const bool isq = bid < 2048;
    const float sc = isq ? qscale : 1.0f;
    const float* src = isq ? q : k;
    u16* dst = isq ? qB : kB;
    int i = ((isq ? bid : bid - 2048) * 256 + tid) * 8;
    float4 v0 = *(const float4*)(src + i);
    float4 v1 = *(const float4*)(src + i + 4);
    uint4 w;
    w.x = cvtpk(v0.x * sc, v0.y * sc);
    w.y = cvtpk(v0.z * sc, v0.w * sc);
    w.z = cvtpk(v1.x * sc, v1.y * sc);
    w.w = cvtpk(v1.z * sc, v1.w * sc);
    *(uint4*)(dst + i) = w;
    return;
  }
  if (bid < 5120) {
    __shared__ float t[64][65];
    int b = bid - 4096;
    int h = b >> 6, s0 = (b & 63) << 6;       // this block = exactly one 64-key tile
    int tile = h * 64 + (b & 63);
    int r = tid >> 2, c0 = (tid & 3) << 4;
    const float* src = v + ((size_t)h * SLEN + s0 + r) * DH + c0;
#pragma unroll
    for (int j = 0; j < 16; j += 4) {
      float4 a = *(const float4*)(src + j);
      t[r][c0 + j]     = a.x;
      t[r][c0 + j + 1] = a.y;
      t[r][c0 + j + 2] = a.z;
      t[r][c0 + j + 3] = a.w;
    }
    __syncthreads();
    int d = tid >> 2, j0 = (tid & 3) << 4;    // j0 in {0,16,32,48}
    int grp  = j0 & 32;
    int half = (j0 & 16) ? 4 : 0;
    u16* dst = vtB + ((size_t)tile * 64 + d) * 64 + grp;
#pragma unroll
    for (int q4 = 0; q4 < 4; ++q4) {
      uint2 val;
      val.x = cvtpk(t[j0 + 4 * q4 + 0][d], t[j0 + 4 * q4 + 1][d]);
      val.y = cvtpk(t[j0 + 4 * q4 + 2][d], t[j0 + 4 * q4 + 3][d]);
      *(uint2*)(dst + 8 * q4 + half) = val;   // key j0+4q4+i -> slot grp+8q4+half+i
    }
    return;
  }
  // ---- meta block ----
  const int G = imin(nGp[0], GMAX);
  for (int s = tid; s < SLEN; s += 256) {
    unsigned char b = (unsigned char)((pmask[s] ? 1 : 0) | (gmask[s] ? 2 : 0));
    msk[s] = b;
  }
  for (int s = SLEN + tid; s < SLEN + 64; s += 256) msk[s] = 0;
  __syncthreads();
  if (tid < 64) {
    int lane = tid;
    if (lane < GMAX) gmsk[lane] = 0;
    int cnt = 0;
    for (int c = 0; c < SLEN / 64 && cnt < G; ++c) {
      int s = c * 64 + lane;
      bool isg = gmask[s] != 0;
      u64 b = __ballot(isg);
      int rank = cnt + (int)__popcll(b & ((1ull << lane) - 1ull));
      if (isg && rank < G) gpos[rank] = s;
      cnt += (int)__popcll(b);
    }
    if (cnt < G) {
      int fill = cnt;
      for (int c = 0; c < SLEN / 64 && fill < G; ++c) {
        int s = c * 64 + lane;
        bool non = gmask[s] == 0;
        u64 b = __ballot(non);
        int rank = fill + (int)__popcll(b & ((1ull << lane) - 1ull));
        if (non && rank < G) gpos[rank] = s;
        fill += (int)__popcll(b);
      }
    }
  }
  __syncthreads();
  if (tid < 64) {
    if (tid < G) {
      int p = gpos[tid];
      gmsk[tid] = (unsigned char)(pmask[p] ? 1 : 0);
      msk[p] = (unsigned char)(msk[p] | 4);
    }
  } else if (tid >= 128) {
    int c = tid - 128;
    if (c < SLEN / 32) {
      unsigned char ok1 = 1, ok2 = 1;
      for (int kk = 0; kk < 32; ++kk) {
        unsigned char b = msk[c * 32 + kk];
        ok1 &= (unsigned char)(((b & 3) == 1) ? 1 : 0);
        ok2 &= (unsigned char)(b & 1);
      }
      cleanmap[c] = (unsigned char)(ok1 | (ok2 << 1));
    }
  }
}

// ---------------- prep2: gather global K/Q rows and Vt cols (tiled source) ----------------
__global__ void lf_gather(const u16* __restrict__ qB, const u16* __restrict__ kB,
                          const u16* __restrict__ vtB, const int* __restrict__ gpos,
                          const int* __restrict__ nGp,
                          u16* __restrict__ gq, u16* __restrict__ gk, u16* __restrict__ gvt) {
  const int G = imin(nGp[0], GMAX);
  int idx = blockIdx.x * 256 + threadIdx.x;
  int h = idx >> 12, m = (idx >> 6) & 63, d = idx & 63;
  size_t oq = ((size_t)h * GMAX + m) * DH + d;
  int r = m & 31;
  int pos = ((r & 12) << 1) + ((r & 16) >> 2) + (r & 3);   // sigma slot within 32-group
  size_t ot = ((size_t)h * DH + d) * GMAX + (m & 32) + pos; // gvt tile: [h][d][64]
  if (m < G) {
    int p = gpos[m];
    int pr = p & 31;
    int ppos = ((pr & 12) << 1) + ((pr & 16) >> 2) + (pr & 3);
    gq[oq]  = qB[((size_t)h * SLEN + p) * DH + d];
    gk[oq]  = kB[((size_t)h * SLEN + p) * DH + d];
    gvt[ot] = vtB[((size_t)(h * 64 + (p >> 6)) * 64 + d) * 64 + (p & 32) + ppos];
  } else {
    gq[oq] = 0; gk[oq] = 0; gvt[ot] = 0;
  }
}

// ---------------- main fused attention ----------------
// Grid: 2176 blocks. wg = XCD-swizzled id; wg%17==0 -> global-rows block (128, key-split 2x),
// else local (2048): 32 queries, 4 waves = (qw) x (ks key split). Fixed-max softmax.
// PV path: P stays in-lane (sigma-permuted, TILED V), no LDS in the main loop.
__global__ __launch_bounds__(256) void lf_attn(
    const u16* __restrict__ qB, const u16* __restrict__ kB, const u16* __restrict__ vtB,
    const u16* __restrict__ gkB, const u16* __restrict__ gqB, const u16* __restrict__ gvtB,
    const int* __restrict__ gpos, const unsigned char* __restrict__ gmskA,
    const unsigned char* __restrict__ mskA, const unsigned char* __restrict__ cleanA,
    const int* __restrict__ nGp, float* __restrict__ out,
    float* __restrict__ pAcc, float* __restrict__ pL) {
  __shared__ __align__(16) float sMrg[3][16][68];
  __shared__ float sLm[3][16];

  const int tid  = threadIdx.x;
  const int wv   = tid >> 6;
  const int lane = tid & 63;
  const int ql   = lane & 15;
  const int g    = lane >> 4;
  const float NEGV = -1e30f;
  const float MEXP = 24.0f;

  const int wg = ((int)blockIdx.x & 7) * 272 + ((int)blockIdx.x >> 3);
  const bool gblk = (wg % 17) == 0;
  const int G = imin(nGp[0], GMAX);

  f32x4 acc[4];
#pragma unroll
  for (int i = 0; i < 4; ++i) acc[i] = (f32x4){0.f, 0.f, 0.f, 0.f};
  f32x4 lsv = (f32x4){0.f, 0.f, 0.f, 0.f};

  bf16x8 qf0, qf1;

  auto SCORE4 = [&](const u16* base, int kb, f32x4 (&sc)[4]) {
#pragma unroll
    for (int t = 0; t < 4; ++t) {
      bf16x8 a0 = *(const bf16x8*)(base + (size_t)(kb + 16 * t + ql) * DH + 8 * g);
      bf16x8 a1 = *(const bf16x8*)(base + (size_t)(kb + 16 * t + ql) * DH + 32 + 8 * g);
      sc[t] = MFMA16(a0, qf0, sc[t]);
      sc[t] = MFMA16(a1, qf1, sc[t]);
    }
  };
  // PV accumulate from one 64-key tile (8KB contiguous). B-frag built in-lane (sigma layout).
  auto PVACC = [&](const u16* tileB, const f32x4 (&pv)[4]) {
#pragma unroll
    for (int s2 = 0; s2 < 2; ++s2) {
      union { u32 w[4]; bf16x8 v8; } u;
      u.w[0] = cvtpk(pv[2 * s2][0], pv[2 * s2][1]);
      u.w[1] = cvtpk(pv[2 * s2][2], pv[2 * s2][3]);
      u.w[2] = cvtpk(pv[2 * s2 + 1][0], pv[2 * s2 + 1][1]);
      u.w[3] = cvtpk(pv[2 * s2 + 1][2], pv[2 * s2 + 1][3]);
#pragma unroll
      for (int dt = 0; dt < 4; ++dt) {
        bf16x8 vf = *(const bf16x8*)(tileB + (size_t)(dt * 16 + ql) * 64 + 32 * s2 + 8 * g);
        acc[dt] = MFMA16(vf, u.v8, acc[dt]);
      }
    }
  };

  if (!gblk) {
    // ---------- local path ----------
    const int lid = wg - wg / 17 - 1;          // 0..2047
    const int h   = lid >> 7;
    const int s0  = (lid & 127) << 5;
    const int qw  = wv >> 1;
    const int ks  = wv & 1;
    const int s0w = s0 + qw * 16;
    const int sq  = s0w + ql;

    const u16* kRow   = kB  + (size_t)h * SLEN * DH;
    const u16* vtHead = vtB + (size_t)h * 64 * 4096;       // 64 tiles of 4096 el per head
    const u16* qRow   = qB  + ((size_t)h * SLEN + sq) * DH;
    qf0 = *(const bf16x8*)(qRow + 8 * g);
    qf1 = *(const bf16x8*)(qRow + 32 + 8 * g);

    if (ks == 0 && G > 0) {
      f32x4 sc[4];
#pragma unroll
      for (int t = 0; t < 4; ++t) sc[t] = (f32x4){0.f, 0.f, 0.f, 0.f};
      SCORE4(gkB + (size_t)h * GMAX * DH, 0, sc);
      f32x4 pv[4];
#pragma unroll
      for (int t = 0; t < 4; ++t) {
        u32 mw = *(const u32*)(gmskA + 16 * t + 4 * g);
#pragma unroll
        for (int i = 0; i < 4; ++i) {
          float s = ((mw >> (8 * i)) & 1) ? sc[t][i] : NEGV;
          pv[t][i] = __builtin_amdgcn_exp2f(s - MEXP);
        }
      }
      lsv += pv[0] + pv[1] + pv[2] + pv[3];
      PVACC(gvtB + (size_t)h * 4096, pv);
    }

    const int start = imax(0, s0 - WW) & ~63;
    const int kbend = imin(SLEN - 1, s0 + 31 + WW);
    for (int kb = start + (ks ? 0 : 64); kb <= kbend; kb += 128) {
      f32x4 sc[4];
#pragma unroll
      for (int t = 0; t < 4; ++t) sc[t] = (f32x4){0.f, 0.f, 0.f, 0.f};
      SCORE4(kRow, kb, sc);
      u16 cw = *(const u16*)(cleanA + (kb >> 5));
      bool cl = ((cw & (cw >> 8) & 1) != 0) &&
                (kb >= s0w + 15 - WW) && (kb + 63 <= s0w + WW);
      f32x4 pv[4];
      if (cl) {
#pragma unroll
        for (int t = 0; t < 4; ++t)
#pragma unroll
          for (int i = 0; i < 4; ++i)
            pv[t][i] = __builtin_amdgcn_exp2f(sc[t][i] - MEXP);
      } else {
#pragma unroll
        for (int t = 0; t < 4; ++t) {
          u32 mw = *(const u32*)(mskA + kb + 16 * t + 4 * g);
#pragma unroll
          for (int i = 0; i < 4; ++i) {
            int kkey = kb + 16 * t + 4 * g + i;
            bool vok = (((mw >> (8 * i)) & 3) == 1) && (kkey >= sq - WW) && (kkey <= sq + WW);
            float s = vok ? sc[t][i] : NEGV;
            pv[t][i] = __builtin_amdgcn_exp2f(s - MEXP);
          }
        }
      }
      lsv += pv[0] + pv[1] + pv[2] + pv[3];
      PVACC(vtHead + (size_t)(kb >> 6) * 4096, pv);
    }

    float lsum = lsv[0] + lsv[1] + lsv[2] + lsv[3];
    lsum += __shfl_xor(lsum, 16);
    lsum += __shfl_xor(lsum, 32);

    if (ks == 1) {
#pragma unroll
      for (int dt = 0; dt < 4; ++dt)
        *(f32x4*)&sMrg[qw][ql][dt * 16 + 4 * g] = acc[dt];
      if (lane < 16) sLm[qw][lane] = lsum;
    }
    __syncthreads();
    if (ks == 0) {
      lsum += sLm[qw][ql];
      float inv = 1.f / lsum;
      bool skip = (mskA[sq] & 4) != 0;
      if (!skip) {
        float* orow = out + ((size_t)h * SLEN + sq) * DH;
#pragma unroll
        for (int dt = 0; dt < 4; ++dt) {
          f32x4 m = *(const f32x4*)&sMrg[qw][ql][dt * 16 + 4 * g];
          f32x4 o = (acc[dt] + m) * inv;
          *(f32x4*)(orow + dt * 16 + 4 * g) = o;
        }
      }
    }
    return;
  }

  // ---------- global-rows path: key-split in half, partials to workspace ----------
  const int gb   = wg / 17;                  // 0..127
  const int h    = gb >> 3;
  const int sub  = gb & 7;
  const int gq0  = (sub >> 1) << 4;
  const int half = sub & 1;
  if (gq0 >= G) return;

  const u16* qRow = gqB + ((size_t)h * GMAX + gq0 + ql) * DH;
  qf0 = *(const bf16x8*)(qRow + 8 * g);
  qf1 = *(const bf16x8*)(qRow + 32 + 8 * g);
  const u16* kRow   = kB  + (size_t)h * SLEN * DH;
  const u16* vtHead = vtB + (size_t)h * 64 * 4096;

  for (int c = 0; c < 8; ++c) {
    int kb = half * 2048 + (wv << 9) + (c << 6);
    f32x4 sc[4];
#pragma unroll
    for (int t = 0; t < 4; ++t) sc[t] = (f32x4){0.f, 0.f, 0.f, 0.f};
    SCORE4(kRow, kb, sc);
    u16 cw = *(const u16*)(cleanA + (kb >> 5));
    bool cl = ((cw & (cw >> 8) & 2) != 0);
    f32x4 pv[4];
    if (cl) {
#pragma unroll
      for (int t = 0; t < 4; ++t)
#pragma unroll
        for (int i = 0; i < 4; ++i)
          pv[t][i] = __builtin_amdgcn_exp2f(sc[t][i] - MEXP);
    } else {
#pragma unroll
      for (int t = 0; t < 4; ++t) {
        u32 mw = *(const u32*)(mskA + kb + 16 * t + 4 * g);
#pragma unroll
        for (int i = 0; i < 4; ++i) {
          float s = ((mw >> (8 * i)) & 1) ? sc[t][i] : NEGV;
          pv[t][i] = __builtin_amdgcn_exp2f(s - MEXP);
        }
      }
    }
    lsv += pv[0] + pv[1] + pv[2] + pv[3];
    PVACC(vtHead + (size_t)(kb >> 6) * 4096, pv);
  }

  float lsum = lsv[0] + lsv[1] + lsv[2] + lsv[3];
  lsum += __shfl_xor(lsum, 16);
  lsum += __shfl_xor(lsum, 32);

  if (wv > 0) {
#pragma unroll
    for (int dt = 0; dt < 4; ++dt)
      *(f32x4*)&sMrg[wv - 1][ql][dt * 16 + 4 * g] = acc[dt];
    if (lane < 16) sLm[wv - 1][lane] = lsum;
  }
  __syncthreads();
  if (wv == 0) {
    lsum += sLm[0][ql] + sLm[1][ql] + sLm[2][ql];
    float* pa = pAcc + ((size_t)gb * 16 + ql) * 64;
#pragma unroll
    for (int dt = 0; dt < 4; ++dt) {
      f32x4 m0 = *(const f32x4*)&sMrg[0][ql][dt * 16 + 4 * g];
      f32x4 m1 = *(const f32x4*)&sMrg[1][ql][dt * 16 + 4 * g];
      f32x4 m2 = *(const f32x4*)&sMrg[2][ql][dt * 16 + 4 * g];
      *(f32x4*)&pa[dt * 16 + 4 * g] = acc[dt] + m0 + m1 + m2;
    }
    if (g == 0) pL[gb * 16 + ql] = lsum;
  }
}

// ---------------- merge the two key-halves of global rows ----------------
__global__ void lf_gmerge(const float* __restrict__ pAcc, const float* __restrict__ pL,
                          const int* __restrict__ gpos, const int* __restrict__ nGp,
                          float* __restrict__ out) {
  const int G = imin(nGp[0], GMAX);
  int b = blockIdx.x;                  // h*4 + gq0i
  int h = b >> 2, gq0 = (b & 3) << 4;
  int t = threadIdx.x;
  int qg = gq0 + (t >> 4);
  int d4 = (t & 15) << 2;
  if (qg >= G) return;
  int q = t >> 4;
  int gb0 = b << 1, gb1 = gb0 + 1;
  float L = pL[gb0 * 16 + q] + pL[gb1 * 16 + q];
  f32x4 a0 = *(const f32x4*)&pAcc[((size_t)gb0 * 16 + q) * 64 + d4];
  f32x4 a1 = *(const f32x4*)&pAcc[((size_t)gb1 * 16 + q) * 64 + d4];
  f32x4 o = (a0 + a1) * (1.f / L);
  *(f32x4*)&out[((size_t)h * SLEN + gpos[qg]) * DH + d4] = o;
}

// ---------------- launch ----------------
extern "C" void kernel_launch(void* const* d_in, const int* in_sizes, int n_in,
                              void* d_out, int out_size, void* d_ws, size_t ws_size,
                              hipStream_t stream) {
  const float* q = (const float*)d_in[0];
  const float* k = (const float*)d_in[1];
  const float* v = (const float*)d_in[2];
  const int* gmask = (const int*)d_in[3];
  const int* pmask = (const int*)d_in[4];
  const int* nGp = (const int*)d_in[5];
  float* out = (float*)d_out;
  char* ws = (char*)d_ws;

  constexpr size_t NEL = (size_t)NH * SLEN * DH;
  constexpr size_t OFF_QBF  = 0;
  constexpr size_t OFF_KBF  = OFF_QBF + NEL * 2;
  constexpr size_t OFF_VTBF = OFF_KBF + NEL * 2;
  constexpr size_t OFF_GK   = OFF_VTBF + NEL * 2 + 256;
  constexpr size_t OFF_GQ   = OFF_GK + (size_t)NH * GMAX * DH * 2;
  constexpr size_t OFF_GVT  = OFF_GQ + (size_t)NH * GMAX * DH * 2;
  constexpr size_t OFF_GPOS = OFF_GVT + (size_t)NH * DH * GMAX * 2;
  constexpr size_t OFF_GMSK = OFF_GPOS + 256;
  constexpr size_t OFF_MSK  = OFF_GMSK + 64;
  constexpr size_t OFF_CLEAN = OFF_MSK + SLEN + 64;
  constexpr size_t OFF_PACC = OFF_CLEAN + 256;
  constexpr size_t OFF_PL   = OFF_PACC + (size_t)128 * 16 * 64 * 4;

  u16* qB  = (u16*)(ws + OFF_QBF);
  u16* kB  = (u16*)(ws + OFF_KBF);
  u16* vtB = (u16*)(ws + OFF_VTBF);
  u16* gk  = (u16*)(ws + OFF_GK);
  u16* gq  = (u16*)(ws + OFF_GQ);
  u16* gvt = (u16*)(ws + OFF_GVT);
  int* gpos = (int*)(ws + OFF_GPOS);
  unsigned char* gmsk = (unsigned char*)(ws + OFF_GMSK);
  unsigned char* msk  = (unsigned char*)(ws + OFF_MSK);
  unsigned char* clean = (unsigned char*)(ws + OFF_CLEAN);
  float* pAcc = (float*)(ws + OFF_PACC);
  float* pL   = (float*)(ws + OFF_PL);

  const float qscale = 0.125f * 1.4426950408889634f;  // 1/sqrt(64) * log2(e)

  lf_prep1<<<5121, 256, 0, stream>>>(q, k, v, gmask, pmask, nGp,
                                     qB, kB, vtB, gpos, gmsk, msk, clean, qscale);
  lf_gather<<<256, 256, 0, stream>>>(qB, kB, vtB, gpos, nGp, gq, gk, gvt);
  lf_attn<<<2176, 256, 0, stream>>>(qB, kB, vtB, gk, gq, gvt, gpos, gmsk, msk, clean,
                                    nGp, out, pAcc, pL);
  lf_gmerge<<<64, 256, 0, stream>>>(pAcc, pL, gpos, nGp, out);
}

// Round 5
// 62.854 us; speedup vs baseline: 2.1635x; 1.8347x over previous
//
#include <hip/hip_runtime.h>
#include <hip/hip_bf16.h>

#define SLEN 4096
#define NH   16
#define DH   64
#define WW   256
#define GMAX 64

typedef unsigned short u16;
typedef unsigned int   u32;
typedef unsigned long long u64;
typedef __attribute__((ext_vector_type(8))) short bf16x8;
typedef __attribute__((ext_vector_type(4))) float f32x4;

#define MFMA16(a,b,c) __builtin_amdgcn_mfma_f32_16x16x32_bf16((a),(b),(c),0,0,0)

static __device__ __forceinline__ int imin(int a, int b) { return a < b ? a : b; }
static __device__ __forceinline__ int imax(int a, int b) { return a > b ? a : b; }

__device__ __forceinline__ u32 cvtpk(float lo, float hi) {
  u32 r;
  asm("v_cvt_pk_bf16_f32 %0, %1, %2" : "=v"(r) : "v"(lo), "v"(hi));
  return r;
}

// async global->LDS, 16B per lane; lds base must be wave-uniform
__device__ __forceinline__ void gload16(const u16* src, u16* lds_base) {
  __builtin_amdgcn_global_load_lds((const __attribute__((address_space(1))) u32*)src,
                                   (__attribute__((address_space(3))) u32*)lds_base,
                                   16, 0, 0);
}

// ---------------- prep1: fused q/k bf16-convert + V transpose (tiled, σ-permuted) + meta ----
// V tile layout: vtB[((h*64 + s/64)*64 + d)*64 + sigma_slot(s%64)]  (one 8KB tile per 64 keys)
__global__ __launch_bounds__(256) void lf_prep1(
    const float* __restrict__ q, const float* __restrict__ k, const float* __restrict__ v,
    const int* __restrict__ gmask, const int* __restrict__ pmask, const int* __restrict__ nGp,
    u16* __restrict__ qB, u16* __restrict__ kB, u16* __restrict__ vtB,
    int* __restrict__ gpos, unsigned char* __restrict__ gmsk,
    unsigned char* __restrict__ msk, unsigned char* __restrict__ cleanmap, float qscale) {
  const int bid = blockIdx.x;
  const int tid = threadIdx.x;
  if (bid < 4096) {
    const bool isq = bid < 2048;
    const float sc = isq ? qscale : 1.0f;
    const float* src = isq ? q : k;
    u16* dst = isq ? qB : kB;
    int i = ((isq ? bid : bid - 2048) * 256 + tid) * 8;
    float4 v0 = *(const float4*)(src + i);
    float4 v1 = *(const float4*)(src + i + 4);
    uint4 w;
    w.x = cvtpk(v0.x * sc, v0.y * sc);
    w.y = cvtpk(v0.z * sc, v0.w * sc);
    w.z = cvtpk(v1.x * sc, v1.y * sc);
    w.w = cvtpk(v1.z * sc, v1.w * sc);
    *(uint4*)(dst + i) = w;
    return;
  }
  if (bid < 5120) {
    __shared__ float t[64][65];
    int b = bid - 4096;
    int h = b >> 6, s0 = (b & 63) << 6;
    int tile = h * 64 + (b & 63);
    int r = tid >> 2, c0 = (tid & 3) << 4;
    const float* src = v + ((size_t)h * SLEN + s0 + r) * DH + c0;
#pragma unroll
    for (int j = 0; j < 16; j += 4) {
      float4 a = *(const float4*)(src + j);
      t[r][c0 + j]     = a.x;
      t[r][c0 + j + 1] = a.y;
      t[r][c0 + j + 2] = a.z;
      t[r][c0 + j + 3] = a.w;
    }
    __syncthreads();
    int d = tid >> 2, j0 = (tid & 3) << 4;
    int grp  = j0 & 32;
    int half = (j0 & 16) ? 4 : 0;
    u16* dst = vtB + ((size_t)tile * 64 + d) * 64 + grp;
#pragma unroll
    for (int q4 = 0; q4 < 4; ++q4) {
      uint2 val;
      val.x = cvtpk(t[j0 + 4 * q4 + 0][d], t[j0 + 4 * q4 + 1][d]);
      val.y = cvtpk(t[j0 + 4 * q4 + 2][d], t[j0 + 4 * q4 + 3][d]);
      *(uint2*)(dst + 8 * q4 + half) = val;
    }
    return;
  }
  // ---- meta block ----
  const int G = imin(nGp[0], GMAX);
  for (int s = tid; s < SLEN; s += 256) {
    unsigned char b = (unsigned char)((pmask[s] ? 1 : 0) | (gmask[s] ? 2 : 0));
    msk[s] = b;
  }
  for (int s = SLEN + tid; s < SLEN + 64; s += 256) msk[s] = 0;
  __syncthreads();
  if (tid < 64) {
    int lane = tid;
    if (lane < GMAX) gmsk[lane] = 0;
    int cnt = 0;
    for (int c = 0; c < SLEN / 64 && cnt < G; ++c) {
      int s = c * 64 + lane;
      bool isg = gmask[s] != 0;
      u64 b = __ballot(isg);
      int rank = cnt + (int)__popcll(b & ((1ull << lane) - 1ull));
      if (isg && rank < G) gpos[rank] = s;
      cnt += (int)__popcll(b);
    }
    if (cnt < G) {
      int fill = cnt;
      for (int c = 0; c < SLEN / 64 && fill < G; ++c) {
        int s = c * 64 + lane;
        bool non = gmask[s] == 0;
        u64 b = __ballot(non);
        int rank = fill + (int)__popcll(b & ((1ull << lane) - 1ull));
        if (non && rank < G) gpos[rank] = s;
        fill += (int)__popcll(b);
      }
    }
  }
  __syncthreads();
  if (tid < 64) {
    if (tid < G) {
      int p = gpos[tid];
      gmsk[tid] = (unsigned char)(pmask[p] ? 1 : 0);
      msk[p] = (unsigned char)(msk[p] | 4);
    }
  } else if (tid >= 128) {
    int c = tid - 128;
    if (c < SLEN / 32) {
      unsigned char ok1 = 1, ok2 = 1;
      for (int kk = 0; kk < 32; ++kk) {
        unsigned char b = msk[c * 32 + kk];
        ok1 &= (unsigned char)(((b & 3) == 1) ? 1 : 0);
        ok2 &= (unsigned char)(b & 1);
      }
      cleanmap[c] = (unsigned char)(ok1 | (ok2 << 1));
    }
  }
}

// ---------------- prep2: gather global K/Q rows and Vt cols (tiled source) ----------------
__global__ void lf_gather(const u16* __restrict__ qB, const u16* __restrict__ kB,
                          const u16* __restrict__ vtB, const int* __restrict__ gpos,
                          const int* __restrict__ nGp,
                          u16* __restrict__ gq, u16* __restrict__ gk, u16* __restrict__ gvt) {
  const int G = imin(nGp[0], GMAX);
  int idx = blockIdx.x * 256 + threadIdx.x;
  int h = idx >> 12, m = (idx >> 6) & 63, d = idx & 63;
  size_t oq = ((size_t)h * GMAX + m) * DH + d;
  int r = m & 31;
  int pos = ((r & 12) << 1) + ((r & 16) >> 2) + (r & 3);
  size_t ot = ((size_t)h * DH + d) * GMAX + (m & 32) + pos;
  if (m < G) {
    int p = gpos[m];
    int pr = p & 31;
    int ppos = ((pr & 12) << 1) + ((pr & 16) >> 2) + (pr & 3);
    gq[oq]  = qB[((size_t)h * SLEN + p) * DH + d];
    gk[oq]  = kB[((size_t)h * SLEN + p) * DH + d];
    gvt[ot] = vtB[((size_t)(h * 64 + (p >> 6)) * 64 + d) * 64 + (p & 32) + ppos];
  } else {
    gq[oq] = 0; gk[oq] = 0; gvt[ot] = 0;
  }
}

// ---------------- unified attention: LDS-staged, block-cooperative ----------------
// 576 blocks x 512 thr. wg = XCD-swizzled; wg%9==0 -> global-rows block (64), else local (512).
// Local block: 128 queries (8 waves x 16q); pipeline over <=11 tiles of 64 keys (incl gtile),
// each tile staged ONCE into dbuf LDS via global_load_lds and consumed by all waves.
// Glob block: (head, keysplit/4); 8 waves = 4 qgroups x 2 key-parities; 16 tiles; partials out.
__global__ __launch_bounds__(512) void lf_attn(
    const u16* __restrict__ qB, const u16* __restrict__ kB, const u16* __restrict__ vtB,
    const u16* __restrict__ gkB, const u16* __restrict__ gqB, const u16* __restrict__ gvtB,
    const unsigned char* __restrict__ gmskA, const unsigned char* __restrict__ mskA,
    const unsigned char* __restrict__ cleanA, const int* __restrict__ nGp,
    float* __restrict__ out, float* __restrict__ pAcc, float* __restrict__ pL) {
  __shared__ __align__(16) u16 sK[2][4096];
  __shared__ __align__(16) u16 sV[2][4096];

  const int tid  = threadIdx.x;
  const int wv   = tid >> 6;
  const int lane = tid & 63;
  const int ql   = lane & 15;
  const int g    = lane >> 4;
  const float NEGV = -1e30f;
  const float MEXP = 24.0f;
  const int G = imin(nGp[0], GMAX);

  const int wg = ((int)blockIdx.x & 7) * 72 + ((int)blockIdx.x >> 3);
  const bool glob = (wg % 9) == 0;

  // per-lane swizzled LDS offsets (elements); same table serves K and V reads
  int off[4][2];
#pragma unroll
  for (int t = 0; t < 4; ++t)
#pragma unroll
    for (int c = 0; c < 2; ++c) {
      int row = 16 * t + ql;
      off[t][c] = (row * 8 + ((c * 4 + g) ^ (row & 7))) * 8;
    }

  f32x4 acc[4];
#pragma unroll
  for (int i = 0; i < 4; ++i) acc[i] = (f32x4){0.f, 0.f, 0.f, 0.f};
  f32x4 lsv = (f32x4){0.f, 0.f, 0.f, 0.f};
  bf16x8 qf0, qf1;

  int h, s0w = 0, sq = 0, t0, nPh, par = 0, qg = 0, splitIdx = 0;
  int lo_w = 0, hi_w = 0;
  bool hasG = false;
  const u16 *gks = nullptr, *gvs = nullptr;

  if (!glob) {
    int lid = wg - wg / 9 - 1;           // 0..511
    h = lid >> 5;
    int qblk = lid & 31;
    int s0 = qblk << 7;
    s0w = s0 + 16 * wv; sq = s0w + ql;
    t0 = imax(0, 2 * qblk - 4);
    int t1 = imin(63, 2 * qblk + 5);
    nPh = t1 - t0 + 1;
    hasG = (G > 0);
    lo_w = imax(t0, (s0w - WW) >> 6);
    hi_w = imin(t1, (s0w + 15 + WW) >> 6);
    const u16* qRow = qB + ((size_t)h * SLEN + sq) * DH;
    qf0 = *(const bf16x8*)(qRow + 8 * g);
    qf1 = *(const bf16x8*)(qRow + 32 + 8 * g);
    gks = gkB + (size_t)h * GMAX * DH;
    gvs = gvtB + (size_t)h * 4096;
  } else {
    int gb = wg / 9;                     // 0..63
    h = gb >> 2; splitIdx = gb & 3;
    int qgrp = wv >> 1; par = wv & 1;
    qg = qgrp * 16 + ql;
    t0 = splitIdx * 16; nPh = 16;
    const u16* qRow = gqB + ((size_t)h * GMAX + qg) * DH;
    qf0 = *(const bf16x8*)(qRow + 8 * g);
    qf1 = *(const bf16x8*)(qRow + 32 + 8 * g);
  }
  const u16* kbase = kB  + (size_t)h * 64 * 4096;
  const u16* vbase = vtB + (size_t)h * 64 * 4096;
  const int totPh = nPh + (hasG ? 1 : 0);

  // stage phase p into buffer b: 1 K-instr + 1 V-instr per wave (1KB each), src pre-swizzled
  auto stage = [&](int p, int b) {
    const u16 *ks, *vs;
    if (hasG && p == 0) { ks = gks; vs = gvs; }
    else {
      int tv = t0 + p - (hasG ? 1 : 0);
      ks = kbase + (size_t)tv * 4096;
      vs = vbase + (size_t)tv * 4096;
    }
    int gran = (wv << 6) + lane;
    int sg = gran ^ ((gran >> 3) & 7);
    gload16(ks + (size_t)sg * 8, &sK[b][wv * 512]);
    gload16(vs + (size_t)sg * 8, &sV[b][wv * 512]);
  };

  auto compute = [&](int p) {
    const bool isg = (hasG && p == 0);
    const int tv = t0 + p - (hasG ? 1 : 0);
    const int kb = tv * 64;
    bool doC = glob ? ((p & 1) == par) : (isg || (tv >= lo_w && tv <= hi_w));
    if (!doC) return;
    const u16* sk = &sK[p & 1][0];
    const u16* sv = &sV[p & 1][0];
    f32x4 sc[4];
#pragma unroll
    for (int t = 0; t < 4; ++t) sc[t] = (f32x4){0.f, 0.f, 0.f, 0.f};
#pragma unroll
    for (int t = 0; t < 4; ++t) {
      bf16x8 a0 = *(const bf16x8*)(sk + off[t][0]);
      bf16x8 a1 = *(const bf16x8*)(sk + off[t][1]);
      sc[t] = MFMA16(a0, qf0, sc[t]);
      sc[t] = MFMA16(a1, qf1, sc[t]);
    }
    f32x4 pv[4];
    if (isg) {
#pragma unroll
      for (int t = 0; t < 4; ++t) {
        u32 mw = *(const u32*)(gmskA + 16 * t + 4 * g);
#pragma unroll
        for (int i = 0; i < 4; ++i) {
          float s = ((mw >> (8 * i)) & 1) ? sc[t][i] : NEGV;
          pv[t][i] = __builtin_amdgcn_exp2f(s - MEXP);
        }
      }
    } else if (glob) {
      u16 cw = *(const u16*)(cleanA + (kb >> 5));
      if (cw & (cw >> 8) & 2) {
#pragma unroll
        for (int t = 0; t < 4; ++t)
#pragma unroll
          for (int i = 0; i < 4; ++i)
            pv[t][i] = __builtin_amdgcn_exp2f(sc[t][i] - MEXP);
      } else {
#pragma unroll
        for (int t = 0; t < 4; ++t) {
          u32 mw = *(const u32*)(mskA + kb + 16 * t + 4 * g);
#pragma unroll
          for (int i = 0; i < 4; ++i) {
            float s = ((mw >> (8 * i)) & 1) ? sc[t][i] : NEGV;
            pv[t][i] = __builtin_amdgcn_exp2f(s - MEXP);
          }
        }
      }
    } else {
      u16 cw = *(const u16*)(cleanA + (kb >> 5));
      bool cl = ((cw & (cw >> 8) & 1) != 0) &&
                (kb >= s0w + 15 - WW) && (kb + 63 <= s0w + WW);
      if (cl) {
#pragma unroll
        for (int t = 0; t < 4; ++t)
#pragma unroll
          for (int i = 0; i < 4; ++i)
            pv[t][i] = __builtin_amdgcn_exp2f(sc[t][i] - MEXP);
      } else {
#pragma unroll
        for (int t = 0; t < 4; ++t) {
          u32 mw = *(const u32*)(mskA + kb + 16 * t + 4 * g);
#pragma unroll
          for (int i = 0; i < 4; ++i) {
            int kkey = kb + 16 * t + 4 * g + i;
            bool vok = (((mw >> (8 * i)) & 3) == 1) && (kkey >= sq - WW) && (kkey <= sq + WW);
            float s = vok ? sc[t][i] : NEGV;
            pv[t][i] = __builtin_amdgcn_exp2f(s - MEXP);
          }
        }
      }
    }
    lsv += pv[0] + pv[1] + pv[2] + pv[3];
#pragma unroll
    for (int s2 = 0; s2 < 2; ++s2) {
      union { u32 w[4]; bf16x8 v8; } u;
      u.w[0] = cvtpk(pv[2 * s2][0], pv[2 * s2][1]);
      u.w[1] = cvtpk(pv[2 * s2][2], pv[2 * s2][3]);
      u.w[2] = cvtpk(pv[2 * s2 + 1][0], pv[2 * s2 + 1][1]);
      u.w[3] = cvtpk(pv[2 * s2 + 1][2], pv[2 * s2 + 1][3]);
#pragma unroll
      for (int dt = 0; dt < 4; ++dt) {
        bf16x8 vf = *(const bf16x8*)(sv + off[dt][s2]);
        acc[dt] = MFMA16(vf, u.v8, acc[dt]);
      }
    }
  };

  // ---- 2-phase pipeline: stage(i+1) || compute(i), counted vmcnt, raw barriers ----
  stage(0, 0);
  for (int p = 0; p < totPh; ++p) {
    if (p + 1 < totPh) {
      stage(p + 1, (p + 1) & 1);
      asm volatile("s_waitcnt vmcnt(2)" ::: "memory");
    } else {
      asm volatile("s_waitcnt vmcnt(0)" ::: "memory");
    }
    __builtin_amdgcn_s_barrier();
    __builtin_amdgcn_sched_barrier(0);
    compute(p);
    __builtin_amdgcn_s_barrier();
  }

  float lsum = lsv[0] + lsv[1] + lsv[2] + lsv[3];
  lsum += __shfl_xor(lsum, 16);
  lsum += __shfl_xor(lsum, 32);

  if (!glob) {
    float inv = 1.f / lsum;
    bool skip = (mskA[sq] & 4) != 0;
    if (!skip) {
      float* orow = out + ((size_t)h * SLEN + sq) * DH;
#pragma unroll
      for (int dt = 0; dt < 4; ++dt) {
        f32x4 o = acc[dt] * inv;
        *(f32x4*)(orow + dt * 16 + 4 * g) = o;
      }
    }
  } else {
    float* pa = pAcc + ((size_t)(h * 8 + splitIdx * 2 + par) * 64 + qg) * 64;
#pragma unroll
    for (int dt = 0; dt < 4; ++dt)
      *(f32x4*)&pa[dt * 16 + 4 * g] = acc[dt];
    if (g == 0) pL[(h * 8 + splitIdx * 2 + par) * 64 + qg] = lsum;
  }
}

// ---------------- merge the 8 key-splits of global rows ----------------
__global__ void lf_gmerge(const float* __restrict__ pAcc, const float* __restrict__ pL,
                          const int* __restrict__ gpos, const int* __restrict__ nGp,
                          float* __restrict__ out) {
  const int G = imin(nGp[0], GMAX);
  int h = blockIdx.x;
  int tid = threadIdx.x;
#pragma unroll
  for (int it = 0; it < 4; ++it) {
    int v = tid + it * 256;            // 0..1023
    int q = v >> 4, d4 = (v & 15) << 2;
    if (q >= G) continue;
    float L = 0.f;
    f32x4 a = (f32x4){0.f, 0.f, 0.f, 0.f};
#pragma unroll
    for (int s = 0; s < 8; ++s) {
      L += pL[(h * 8 + s) * 64 + q];
      a += *(const f32x4*)&pAcc[((size_t)(h * 8 + s) * 64 + q) * 64 + d4];
    }
    *(f32x4*)&out[((size_t)h * SLEN + gpos[q]) * DH + d4] = a * (1.f / L);
  }
}

// ---------------- launch ----------------
extern "C" void kernel_launch(void* const* d_in, const int* in_sizes, int n_in,
                              void* d_out, int out_size, void* d_ws, size_t ws_size,
                              hipStream_t stream) {
  const float* q = (const float*)d_in[0];
  const float* k = (const float*)d_in[1];
  const float* v = (const float*)d_in[2];
  const int* gmask = (const int*)d_in[3];
  const int* pmask = (const int*)d_in[4];
  const int* nGp = (const int*)d_in[5];
  float* out = (float*)d_out;
  char* ws = (char*)d_ws;

  constexpr size_t NEL = (size_t)NH * SLEN * DH;
  constexpr size_t OFF_QBF  = 0;
  constexpr size_t OFF_KBF  = OFF_QBF + NEL * 2;
  constexpr size_t OFF_VTBF = OFF_KBF + NEL * 2;
  constexpr size_t OFF_GK   = OFF_VTBF + NEL * 2 + 256;
  constexpr size_t OFF_GQ   = OFF_GK + (size_t)NH * GMAX * DH * 2;
  constexpr size_t OFF_GVT  = OFF_GQ + (size_t)NH * GMAX * DH * 2;
  constexpr size_t OFF_GPOS = OFF_GVT + (size_t)NH * DH * GMAX * 2;
  constexpr size_t OFF_GMSK = OFF_GPOS + 256;
  constexpr size_t OFF_MSK  = OFF_GMSK + 64;
  constexpr size_t OFF_CLEAN = OFF_MSK + SLEN + 64;
  constexpr size_t OFF_PACC = OFF_CLEAN + 256;
  constexpr size_t OFF_PL   = OFF_PACC + (size_t)NH * 8 * 64 * 64 * 4;

  u16* qB  = (u16*)(ws + OFF_QBF);
  u16* kB  = (u16*)(ws + OFF_KBF);
  u16* vtB = (u16*)(ws + OFF_VTBF);
  u16* gk  = (u16*)(ws + OFF_GK);
  u16* gq  = (u16*)(ws + OFF_GQ);
  u16* gvt = (u16*)(ws + OFF_GVT);
  int* gpos = (int*)(ws + OFF_GPOS);
  unsigned char* gmsk = (unsigned char*)(ws + OFF_GMSK);
  unsigned char* msk  = (unsigned char*)(ws + OFF_MSK);
  unsigned char* clean = (unsigned char*)(ws + OFF_CLEAN);
  float* pAcc = (float*)(ws + OFF_PACC);
  float* pL   = (float*)(ws + OFF_PL);

  const float qscale = 0.125f * 1.4426950408889634f;  // 1/sqrt(64) * log2(e)

  lf_prep1<<<5121, 256, 0, stream>>>(q, k, v, gmask, pmask, nGp,
                                     qB, kB, vtB, gpos, gmsk, msk, clean, qscale);
  lf_gather<<<256, 256, 0, stream>>>(qB, kB, vtB, gpos, nGp, gq, gk, gvt);
  lf_attn<<<576, 512, 0, stream>>>(qB, kB, vtB, gk, gq, gvt, gmsk, msk, clean,
                                   nGp, out, pAcc, pL);
  lf_gmerge<<<NH, 256, 0, stream>>>(pAcc, pL, gpos, nGp, out);
}

// Round 6
// 56.747 us; speedup vs baseline: 2.3963x; 1.1076x over previous
//
#include <hip/hip_runtime.h>
#include <hip/hip_bf16.h>

#define SLEN 4096
#define NH   16
#define DH   64
#define WW   256
#define GMAX 64

typedef unsigned short u16;
typedef unsigned int   u32;
typedef unsigned long long u64;
typedef __attribute__((ext_vector_type(8))) short bf16x8;
typedef __attribute__((ext_vector_type(4))) float f32x4;

#define MFMA16(a,b,c) __builtin_amdgcn_mfma_f32_16x16x32_bf16((a),(b),(c),0,0,0)

static __device__ __forceinline__ int imin(int a, int b) { return a < b ? a : b; }
static __device__ __forceinline__ int imax(int a, int b) { return a > b ? a : b; }

__device__ __forceinline__ u32 cvtpk(float lo, float hi) {
  u32 r;
  asm("v_cvt_pk_bf16_f32 %0, %1, %2" : "=v"(r) : "v"(lo), "v"(hi));
  return r;
}

// async global->LDS, 16B per lane; lds base must be wave-uniform
__device__ __forceinline__ void gload16(const u16* src, u16* lds_base) {
  __builtin_amdgcn_global_load_lds((const __attribute__((address_space(1))) u32*)src,
                                   (__attribute__((address_space(3))) u32*)lds_base,
                                   16, 0, 0);
}

// ---------------- prep1: fused q/k bf16-convert + V transpose (tiled, σ-permuted) + meta ----
// V tile layout: vtB[((h*64 + s/64)*64 + d)*64 + sigma_slot(s%64)]  (one 8KB tile per 64 keys)
__global__ __launch_bounds__(256) void lf_prep1(
    const float* __restrict__ q, const float* __restrict__ k, const float* __restrict__ v,
    const int* __restrict__ gmask, const int* __restrict__ pmask, const int* __restrict__ nGp,
    u16* __restrict__ qB, u16* __restrict__ kB, u16* __restrict__ vtB,
    int* __restrict__ gpos, unsigned char* __restrict__ gmsk,
    unsigned char* __restrict__ msk, unsigned char* __restrict__ cleanmap, float qscale) {
  const int bid = blockIdx.x;
  const int tid = threadIdx.x;
  if (bid < 4096) {
    const bool isq = bid < 2048;
    const float sc = isq ? qscale : 1.0f;
    const float* src = isq ? q : k;
    u16* dst = isq ? qB : kB;
    int i = ((isq ? bid : bid - 2048) * 256 + tid) * 8;
    float4 v0 = *(const float4*)(src + i);
    float4 v1 = *(const float4*)(src + i + 4);
    uint4 w;
    w.x = cvtpk(v0.x * sc, v0.y * sc);
    w.y = cvtpk(v0.z * sc, v0.w * sc);
    w.z = cvtpk(v1.x * sc, v1.y * sc);
    w.w = cvtpk(v1.z * sc, v1.w * sc);
    *(uint4*)(dst + i) = w;
    return;
  }
  if (bid < 5120) {
    __shared__ float t[64][65];
    int b = bid - 4096;
    int h = b >> 6, s0 = (b & 63) << 6;
    int tile = h * 64 + (b & 63);
    int r = tid >> 2, c0 = (tid & 3) << 4;
    const float* src = v + ((size_t)h * SLEN + s0 + r) * DH + c0;
#pragma unroll
    for (int j = 0; j < 16; j += 4) {
      float4 a = *(const float4*)(src + j);
      t[r][c0 + j]     = a.x;
      t[r][c0 + j + 1] = a.y;
      t[r][c0 + j + 2] = a.z;
      t[r][c0 + j + 3] = a.w;
    }
    __syncthreads();
    int d = tid >> 2, j0 = (tid & 3) << 4;
    int grp  = j0 & 32;
    int half = (j0 & 16) ? 4 : 0;
    u16* dst = vtB + ((size_t)tile * 64 + d) * 64 + grp;
#pragma unroll
    for (int q4 = 0; q4 < 4; ++q4) {
      uint2 val;
      val.x = cvtpk(t[j0 + 4 * q4 + 0][d], t[j0 + 4 * q4 + 1][d]);
      val.y = cvtpk(t[j0 + 4 * q4 + 2][d], t[j0 + 4 * q4 + 3][d]);
      *(uint2*)(dst + 8 * q4 + half) = val;
    }
    return;
  }
  // ---- meta block ----
  const int G = imin(nGp[0], GMAX);
  for (int s = tid; s < SLEN; s += 256) {
    unsigned char b = (unsigned char)((pmask[s] ? 1 : 0) | (gmask[s] ? 2 : 0));
    msk[s] = b;
  }
  for (int s = SLEN + tid; s < SLEN + 64; s += 256) msk[s] = 0;
  __syncthreads();
  if (tid < 64) {
    int lane = tid;
    if (lane < GMAX) gmsk[lane] = 0;
    int cnt = 0;
    for (int c = 0; c < SLEN / 64 && cnt < G; ++c) {
      int s = c * 64 + lane;
      bool isg = gmask[s] != 0;
      u64 b = __ballot(isg);
      int rank = cnt + (int)__popcll(b & ((1ull << lane) - 1ull));
      if (isg && rank < G) gpos[rank] = s;
      cnt += (int)__popcll(b);
    }
    if (cnt < G) {
      int fill = cnt;
      for (int c = 0; c < SLEN / 64 && fill < G; ++c) {
        int s = c * 64 + lane;
        bool non = gmask[s] == 0;
        u64 b = __ballot(non);
        int rank = fill + (int)__popcll(b & ((1ull << lane) - 1ull));
        if (non && rank < G) gpos[rank] = s;
        fill += (int)__popcll(b);
      }
    }
  }
  __syncthreads();
  if (tid < 64) {
    if (tid < G) {
      int p = gpos[tid];
      gmsk[tid] = (unsigned char)(pmask[p] ? 1 : 0);
      msk[p] = (unsigned char)(msk[p] | 4);
    }
  } else if (tid >= 128) {
    int c = tid - 128;
    if (c < SLEN / 32) {
      unsigned char ok1 = 1, ok2 = 1;
      for (int kk = 0; kk < 32; ++kk) {
        unsigned char b = msk[c * 32 + kk];
        ok1 &= (unsigned char)(((b & 3) == 1) ? 1 : 0);
        ok2 &= (unsigned char)(b & 1);
      }
      cleanmap[c] = (unsigned char)(ok1 | (ok2 << 1));
    }
  }
}

// ---------------- prep2: gather global K/Q rows and Vt cols (tiled source) ----------------
__global__ void lf_gather(const u16* __restrict__ qB, const u16* __restrict__ kB,
                          const u16* __restrict__ vtB, const int* __restrict__ gpos,
                          const int* __restrict__ nGp,
                          u16* __restrict__ gq, u16* __restrict__ gk, u16* __restrict__ gvt) {
  const int G = imin(nGp[0], GMAX);
  int idx = blockIdx.x * 256 + threadIdx.x;
  int h = idx >> 12, m = (idx >> 6) & 63, d = idx & 63;
  size_t oq = ((size_t)h * GMAX + m) * DH + d;
  int r = m & 31;
  int pos = ((r & 12) << 1) + ((r & 16) >> 2) + (r & 3);
  size_t ot = ((size_t)h * DH + d) * GMAX + (m & 32) + pos;
  if (m < G) {
    int p = gpos[m];
    int pr = p & 31;
    int ppos = ((pr & 12) << 1) + ((pr & 16) >> 2) + (pr & 3);
    gq[oq]  = qB[((size_t)h * SLEN + p) * DH + d];
    gk[oq]  = kB[((size_t)h * SLEN + p) * DH + d];
    gvt[ot] = vtB[((size_t)(h * 64 + (p >> 6)) * 64 + d) * 64 + (p & 32) + ppos];
  } else {
    gq[oq] = 0; gk[oq] = 0; gvt[ot] = 0;
  }
}

// ---------------- unified attention: LDS-staged, block-cooperative, 4-wave blocks ----------
// 1152 blocks x 256 thr. wg = XCD-swizzled; wg%9==0 -> global-rows block (128), else local (1024).
// Local block: 64 queries (4 waves x 16q); <=10 tiles of 64 keys (incl gtile), staged once,
// consumed by all 4 waves via double-buffered LDS (32KB).
// Glob block: (head, split/8); 4 waves (= 4 qgroups of the 64 global rows) EACH compute all
// 8 staged tiles; partials to workspace; merged by lf_gmerge.
__global__ __launch_bounds__(256) void lf_attn(
    const u16* __restrict__ qB, const u16* __restrict__ kB, const u16* __restrict__ vtB,
    const u16* __restrict__ gkB, const u16* __restrict__ gqB, const u16* __restrict__ gvtB,
    const unsigned char* __restrict__ gmskA, const unsigned char* __restrict__ mskA,
    const unsigned char* __restrict__ cleanA, const int* __restrict__ nGp,
    float* __restrict__ out, float* __restrict__ pAcc, float* __restrict__ pL) {
  __shared__ __align__(16) u16 sK[2][4096];
  __shared__ __align__(16) u16 sV[2][4096];

  const int tid  = threadIdx.x;
  const int wv   = tid >> 6;
  const int lane = tid & 63;
  const int ql   = lane & 15;
  const int g    = lane >> 4;
  const float NEGV = -1e30f;
  const float MEXP = 24.0f;
  const int G = imin(nGp[0], GMAX);

  const int wg = ((int)blockIdx.x & 7) * 144 + ((int)blockIdx.x >> 3);
  const bool glob = (wg % 9) == 0;

  // per-lane swizzled LDS offsets (elements); same table serves K and V reads
  int off[4][2];
#pragma unroll
  for (int t = 0; t < 4; ++t)
#pragma unroll
    for (int c = 0; c < 2; ++c) {
      int row = 16 * t + ql;
      off[t][c] = (row * 8 + ((c * 4 + g) ^ (row & 7))) * 8;
    }

  f32x4 acc[4];
#pragma unroll
  for (int i = 0; i < 4; ++i) acc[i] = (f32x4){0.f, 0.f, 0.f, 0.f};
  f32x4 lsv = (f32x4){0.f, 0.f, 0.f, 0.f};
  bf16x8 qf0, qf1;

  int h, s0w = 0, sq = 0, t0, nPh, qg = 0, splitIdx = 0;
  int lo_w = 0, hi_w = 0;
  bool hasG = false;
  const u16 *gks = nullptr, *gvs = nullptr;

  if (!glob) {
    int lid = wg - wg / 9 - 1;           // 0..1023
    h = lid >> 6;
    int qblk = lid & 63;
    int s0 = qblk << 6;                  // 64 queries per block
    s0w = s0 + 16 * wv; sq = s0w + ql;
    t0 = imax(0, qblk - 4);
    int t1 = imin(63, qblk + 4);
    nPh = t1 - t0 + 1;
    hasG = (G > 0);
    lo_w = imax(t0, (s0w - WW) >> 6);
    hi_w = imin(t1, (s0w + 15 + WW) >> 6);
    const u16* qRow = qB + ((size_t)h * SLEN + sq) * DH;
    qf0 = *(const bf16x8*)(qRow + 8 * g);
    qf1 = *(const bf16x8*)(qRow + 32 + 8 * g);
    gks = gkB + (size_t)h * GMAX * DH;
    gvs = gvtB + (size_t)h * 4096;
  } else {
    int gb = wg / 9;                     // 0..127
    h = gb >> 3; splitIdx = gb & 7;
    qg = wv * 16 + ql;                   // wave = one 16-query group
    t0 = splitIdx * 8; nPh = 8;
    const u16* qRow = gqB + ((size_t)h * GMAX + qg) * DH;
    qf0 = *(const bf16x8*)(qRow + 8 * g);
    qf1 = *(const bf16x8*)(qRow + 32 + 8 * g);
  }
  const u16* kbase = kB  + (size_t)h * 64 * 4096;
  const u16* vbase = vtB + (size_t)h * 64 * 4096;
  const int totPh = nPh + (hasG ? 1 : 0);

  // stage phase p into buffer b: 2 K-instrs + 2 V-instrs per wave (1KB each), src pre-swizzled
  auto stage = [&](int p, int b) {
    const u16 *ks, *vs;
    if (hasG && p == 0) { ks = gks; vs = gvs; }
    else {
      int tv = t0 + p - (hasG ? 1 : 0);
      ks = kbase + (size_t)tv * 4096;
      vs = vbase + (size_t)tv * 4096;
    }
#pragma unroll
    for (int j = 0; j < 2; ++j) {
      int gran = (wv * 2 + j) * 64 + lane;
      int sg = gran ^ ((gran >> 3) & 7);
      gload16(ks + (size_t)sg * 8, &sK[b][(wv * 2 + j) * 512]);
      gload16(vs + (size_t)sg * 8, &sV[b][(wv * 2 + j) * 512]);
    }
  };

  auto compute = [&](int p) {
    const bool isg = (hasG && p == 0);
    const int tv = t0 + p - (hasG ? 1 : 0);
    const int kb = tv * 64;
    bool doC = glob ? true : (isg || (tv >= lo_w && tv <= hi_w));
    if (!doC) return;
    const u16* sk = &sK[p & 1][0];
    const u16* sv = &sV[p & 1][0];
    f32x4 sc[4];
#pragma unroll
    for (int t = 0; t < 4; ++t) sc[t] = (f32x4){0.f, 0.f, 0.f, 0.f};
#pragma unroll
    for (int t = 0; t < 4; ++t) {
      bf16x8 a0 = *(const bf16x8*)(sk + off[t][0]);
      bf16x8 a1 = *(const bf16x8*)(sk + off[t][1]);
      sc[t] = MFMA16(a0, qf0, sc[t]);
      sc[t] = MFMA16(a1, qf1, sc[t]);
    }
    f32x4 pv[4];
    if (isg) {
#pragma unroll
      for (int t = 0; t < 4; ++t) {
        u32 mw = *(const u32*)(gmskA + 16 * t + 4 * g);
#pragma unroll
        for (int i = 0; i < 4; ++i) {
          float s = ((mw >> (8 * i)) & 1) ? sc[t][i] : NEGV;
          pv[t][i] = __builtin_amdgcn_exp2f(s - MEXP);
        }
      }
    } else if (glob) {
      u16 cw = *(const u16*)(cleanA + (kb >> 5));
      if (cw & (cw >> 8) & 2) {
#pragma unroll
        for (int t = 0; t < 4; ++t)
#pragma unroll
          for (int i = 0; i < 4; ++i)
            pv[t][i] = __builtin_amdgcn_exp2f(sc[t][i] - MEXP);
      } else {
#pragma unroll
        for (int t = 0; t < 4; ++t) {
          u32 mw = *(const u32*)(mskA + kb + 16 * t + 4 * g);
#pragma unroll
          for (int i = 0; i < 4; ++i) {
            float s = ((mw >> (8 * i)) & 1) ? sc[t][i] : NEGV;
            pv[t][i] = __builtin_amdgcn_exp2f(s - MEXP);
          }
        }
      }
    } else {
      u16 cw = *(const u16*)(cleanA + (kb >> 5));
      bool cl = ((cw & (cw >> 8) & 1) != 0) &&
                (kb >= s0w + 15 - WW) && (kb + 63 <= s0w + WW);
      if (cl) {
#pragma unroll
        for (int t = 0; t < 4; ++t)
#pragma unroll
          for (int i = 0; i < 4; ++i)
            pv[t][i] = __builtin_amdgcn_exp2f(sc[t][i] - MEXP);
      } else {
#pragma unroll
        for (int t = 0; t < 4; ++t) {
          u32 mw = *(const u32*)(mskA + kb + 16 * t + 4 * g);
#pragma unroll
          for (int i = 0; i < 4; ++i) {
            int kkey = kb + 16 * t + 4 * g + i;
            bool vok = (((mw >> (8 * i)) & 3) == 1) && (kkey >= sq - WW) && (kkey <= sq + WW);
            float s = vok ? sc[t][i] : NEGV;
            pv[t][i] = __builtin_amdgcn_exp2f(s - MEXP);
          }
        }
      }
    }
    lsv += pv[0] + pv[1] + pv[2] + pv[3];
#pragma unroll
    for (int s2 = 0; s2 < 2; ++s2) {
      union { u32 w[4]; bf16x8 v8; } u;
      u.w[0] = cvtpk(pv[2 * s2][0], pv[2 * s2][1]);
      u.w[1] = cvtpk(pv[2 * s2][2], pv[2 * s2][3]);
      u.w[2] = cvtpk(pv[2 * s2 + 1][0], pv[2 * s2 + 1][1]);
      u.w[3] = cvtpk(pv[2 * s2 + 1][2], pv[2 * s2 + 1][3]);
#pragma unroll
      for (int dt = 0; dt < 4; ++dt) {
        bf16x8 vf = *(const bf16x8*)(sv + off[dt][s2]);
        acc[dt] = MFMA16(vf, u.v8, acc[dt]);
      }
    }
  };

  // ---- 2-phase pipeline: stage(i+1) || compute(i), counted vmcnt, raw barriers ----
  stage(0, 0);
  for (int p = 0; p < totPh; ++p) {
    if (p + 1 < totPh) {
      stage(p + 1, (p + 1) & 1);
      asm volatile("s_waitcnt vmcnt(4)" ::: "memory");
    } else {
      asm volatile("s_waitcnt vmcnt(0)" ::: "memory");
    }
    __builtin_amdgcn_s_barrier();
    __builtin_amdgcn_sched_barrier(0);
    compute(p);
    __builtin_amdgcn_s_barrier();
  }

  float lsum = lsv[0] + lsv[1] + lsv[2] + lsv[3];
  lsum += __shfl_xor(lsum, 16);
  lsum += __shfl_xor(lsum, 32);

  if (!glob) {
    float inv = 1.f / lsum;
    bool skip = (mskA[sq] & 4) != 0;
    if (!skip) {
      float* orow = out + ((size_t)h * SLEN + sq) * DH;
#pragma unroll
      for (int dt = 0; dt < 4; ++dt) {
        f32x4 o = acc[dt] * inv;
        *(f32x4*)(orow + dt * 16 + 4 * g) = o;
      }
    }
  } else {
    float* pa = pAcc + ((size_t)(h * 8 + splitIdx) * 64 + qg) * 64;
#pragma unroll
    for (int dt = 0; dt < 4; ++dt)
      *(f32x4*)&pa[dt * 16 + 4 * g] = acc[dt];
    if (g == 0) pL[(h * 8 + splitIdx) * 64 + qg] = lsum;
  }
}

// ---------------- merge the 8 key-splits of global rows ----------------
__global__ void lf_gmerge(const float* __restrict__ pAcc, const float* __restrict__ pL,
                          const int* __restrict__ gpos, const int* __restrict__ nGp,
                          float* __restrict__ out) {
  const int G = imin(nGp[0], GMAX);
  int h = blockIdx.x;
  int tid = threadIdx.x;
#pragma unroll
  for (int it = 0; it < 4; ++it) {
    int v = tid + it * 256;            // 0..1023
    int q = v >> 4, d4 = (v & 15) << 2;
    if (q >= G) continue;
    float L = 0.f;
    f32x4 a = (f32x4){0.f, 0.f, 0.f, 0.f};
#pragma unroll
    for (int s = 0; s < 8; ++s) {
      L += pL[(h * 8 + s) * 64 + q];
      a += *(const f32x4*)&pAcc[((size_t)(h * 8 + s) * 64 + q) * 64 + d4];
    }
    *(f32x4*)&out[((size_t)h * SLEN + gpos[q]) * DH + d4] = a * (1.f / L);
  }
}

// ---------------- launch ----------------
extern "C" void kernel_launch(void* const* d_in, const int* in_sizes, int n_in,
                              void* d_out, int out_size, void* d_ws, size_t ws_size,
                              hipStream_t stream) {
  const float* q = (const float*)d_in[0];
  const float* k = (const float*)d_in[1];
  const float* v = (const float*)d_in[2];
  const int* gmask = (const int*)d_in[3];
  const int* pmask = (const int*)d_in[4];
  const int* nGp = (const int*)d_in[5];
  float* out = (float*)d_out;
  char* ws = (char*)d_ws;

  constexpr size_t NEL = (size_t)NH * SLEN * DH;
  constexpr size_t OFF_QBF  = 0;
  constexpr size_t OFF_KBF  = OFF_QBF + NEL * 2;
  constexpr size_t OFF_VTBF = OFF_KBF + NEL * 2;
  constexpr size_t OFF_GK   = OFF_VTBF + NEL * 2 + 256;
  constexpr size_t OFF_GQ   = OFF_GK + (size_t)NH * GMAX * DH * 2;
  constexpr size_t OFF_GVT  = OFF_GQ + (size_t)NH * GMAX * DH * 2;
  constexpr size_t OFF_GPOS = OFF_GVT + (size_t)NH * DH * GMAX * 2;
  constexpr size_t OFF_GMSK = OFF_GPOS + 256;
  constexpr size_t OFF_MSK  = OFF_GMSK + 64;
  constexpr size_t OFF_CLEAN = OFF_MSK + SLEN + 64;
  constexpr size_t OFF_PACC = OFF_CLEAN + 256;
  constexpr size_t OFF_PL   = OFF_PACC + (size_t)NH * 8 * 64 * 64 * 4;

  u16* qB  = (u16*)(ws + OFF_QBF);
  u16* kB  = (u16*)(ws + OFF_KBF);
  u16* vtB = (u16*)(ws + OFF_VTBF);
  u16* gk  = (u16*)(ws + OFF_GK);
  u16* gq  = (u16*)(ws + OFF_GQ);
  u16* gvt = (u16*)(ws + OFF_GVT);
  int* gpos = (int*)(ws + OFF_GPOS);
  unsigned char* gmsk = (unsigned char*)(ws + OFF_GMSK);
  unsigned char* msk  = (unsigned char*)(ws + OFF_MSK);
  unsigned char* clean = (unsigned char*)(ws + OFF_CLEAN);
  float* pAcc = (float*)(ws + OFF_PACC);
  float* pL   = (float*)(ws + OFF_PL);

  const float qscale = 0.125f * 1.4426950408889634f;  // 1/sqrt(64) * log2(e)

  lf_prep1<<<5121, 256, 0, stream>>>(q, k, v, gmask, pmask, nGp,
                                     qB, kB, vtB, gpos, gmsk, msk, clean, qscale);
  lf_gather<<<256, 256, 0, stream>>>(qB, kB, vtB, gpos, nGp, gq, gk, gvt);
  lf_attn<<<1152, 256, 0, stream>>>(qB, kB, vtB, gk, gq, gvt, gmsk, msk, clean,
                                    nGp, out, pAcc, pL);
  lf_gmerge<<<NH, 256, 0, stream>>>(pAcc, pL, gpos, nGp, out);
}

// Round 7
// 55.251 us; speedup vs baseline: 2.4612x; 1.0271x over previous
//
#include <hip/hip_runtime.h>
#include <hip/hip_bf16.h>

#define SLEN 4096
#define NH   16
#define DH   64
#define WW   256
#define GMAX 64

typedef unsigned short u16;
typedef unsigned int   u32;
typedef unsigned long long u64;
typedef __attribute__((ext_vector_type(8))) short bf16x8;
typedef __attribute__((ext_vector_type(4))) float f32x4;

#define MFMA16(a,b,c) __builtin_amdgcn_mfma_f32_16x16x32_bf16((a),(b),(c),0,0,0)

static __device__ __forceinline__ int imin(int a, int b) { return a < b ? a : b; }
static __device__ __forceinline__ int imax(int a, int b) { return a > b ? a : b; }

__device__ __forceinline__ u32 cvtpk(float lo, float hi) {
  u32 r;
  asm("v_cvt_pk_bf16_f32 %0, %1, %2" : "=v"(r) : "v"(lo), "v"(hi));
  return r;
}
__device__ __forceinline__ u16 f2bf(float x) {
  u32 u = __float_as_uint(x);
  u32 r = (u + 0x7fffu + ((u >> 16) & 1u)) >> 16;
  return (u16)r;
}

// async global->LDS, 16B per lane; lds base must be wave-uniform
__device__ __forceinline__ void gload16(const u16* src, u16* lds_base) {
  __builtin_amdgcn_global_load_lds((const __attribute__((address_space(1))) u32*)src,
                                   (__attribute__((address_space(3))) u32*)lds_base,
                                   16, 0, 0);
}

// ---------------- prep1: k bf16-convert + V transpose (tiled, σ-permuted) + meta ----------
// grid: [0,2048) k-conv, [2048,3072) v-transpose, 3072 meta
// V tile layout: vtB[((h*64 + s/64)*64 + d)*64 + sigma_slot(s%64)]  (one 8KB tile per 64 keys)
__global__ __launch_bounds__(256) void lf_prep1(
    const float* __restrict__ k, const float* __restrict__ v,
    const int* __restrict__ gmask, const int* __restrict__ pmask, const int* __restrict__ nGp,
    u16* __restrict__ kB, u16* __restrict__ vtB,
    int* __restrict__ gpos, unsigned char* __restrict__ gmsk,
    unsigned char* __restrict__ msk, unsigned char* __restrict__ cleanmap) {
  const int bid = blockIdx.x;
  const int tid = threadIdx.x;
  if (bid < 2048) {
    int i = (bid * 256 + tid) * 8;
    float4 v0 = *(const float4*)(k + i);
    float4 v1 = *(const float4*)(k + i + 4);
    uint4 w;
    w.x = cvtpk(v0.x, v0.y);
    w.y = cvtpk(v0.z, v0.w);
    w.z = cvtpk(v1.x, v1.y);
    w.w = cvtpk(v1.z, v1.w);
    *(uint4*)(kB + i) = w;
    return;
  }
  if (bid < 3072) {
    __shared__ float t[64][65];
    int b = bid - 2048;
    int h = b >> 6, s0 = (b & 63) << 6;
    int tile = h * 64 + (b & 63);
    int r = tid >> 2, c0 = (tid & 3) << 4;
    const float* src = v + ((size_t)h * SLEN + s0 + r) * DH + c0;
#pragma unroll
    for (int j = 0; j < 16; j += 4) {
      float4 a = *(const float4*)(src + j);
      t[r][c0 + j]     = a.x;
      t[r][c0 + j + 1] = a.y;
      t[r][c0 + j + 2] = a.z;
      t[r][c0 + j + 3] = a.w;
    }
    __syncthreads();
    int d = tid >> 2, j0 = (tid & 3) << 4;
    int grp  = j0 & 32;
    int half = (j0 & 16) ? 4 : 0;
    u16* dst = vtB + ((size_t)tile * 64 + d) * 64 + grp;
#pragma unroll
    for (int q4 = 0; q4 < 4; ++q4) {
      uint2 val;
      val.x = cvtpk(t[j0 + 4 * q4 + 0][d], t[j0 + 4 * q4 + 1][d]);
      val.y = cvtpk(t[j0 + 4 * q4 + 2][d], t[j0 + 4 * q4 + 3][d]);
      *(uint2*)(dst + 8 * q4 + half) = val;
    }
    return;
  }
  // ---- meta block ----
  const int G = imin(nGp[0], GMAX);
  for (int s = tid; s < SLEN; s += 256) {
    unsigned char b = (unsigned char)((pmask[s] ? 1 : 0) | (gmask[s] ? 2 : 0));
    msk[s] = b;
  }
  for (int s = SLEN + tid; s < SLEN + 64; s += 256) msk[s] = 0;
  __syncthreads();
  if (tid < 64) {
    int lane = tid;
    if (lane < GMAX) gmsk[lane] = 0;
    int cnt = 0;
    for (int c = 0; c < SLEN / 64 && cnt < G; ++c) {
      int s = c * 64 + lane;
      bool isg = gmask[s] != 0;
      u64 b = __ballot(isg);
      int rank = cnt + (int)__popcll(b & ((1ull << lane) - 1ull));
      if (isg && rank < G) gpos[rank] = s;
      cnt += (int)__popcll(b);
    }
    if (cnt < G) {
      int fill = cnt;
      for (int c = 0; c < SLEN / 64 && fill < G; ++c) {
        int s = c * 64 + lane;
        bool non = gmask[s] == 0;
        u64 b = __ballot(non);
        int rank = fill + (int)__popcll(b & ((1ull << lane) - 1ull));
        if (non && rank < G) gpos[rank] = s;
        fill += (int)__popcll(b);
      }
    }
  }
  __syncthreads();
  if (tid < 64) {
    if (tid < G) {
      int p = gpos[tid];
      gmsk[tid] = (unsigned char)(pmask[p] ? 1 : 0);
      msk[p] = (unsigned char)(msk[p] | 4);
    }
  } else if (tid >= 128) {
    int c = tid - 128;
    if (c < SLEN / 32) {
      unsigned char ok1 = 1, ok2 = 1;
      for (int kk = 0; kk < 32; ++kk) {
        unsigned char b = msk[c * 32 + kk];
        ok1 &= (unsigned char)(((b & 3) == 1) ? 1 : 0);
        ok2 &= (unsigned char)(b & 1);
      }
      cleanmap[c] = (unsigned char)(ok1 | (ok2 << 1));
    }
  }
}

// ---------------- prep2: gather global K/Q rows and Vt cols (tiled source) ----------------
__global__ void lf_gather(const float* __restrict__ qF, const u16* __restrict__ kB,
                          const u16* __restrict__ vtB, const int* __restrict__ gpos,
                          const int* __restrict__ nGp,
                          u16* __restrict__ gq, u16* __restrict__ gk, u16* __restrict__ gvt,
                          float qscale) {
  const int G = imin(nGp[0], GMAX);
  int idx = blockIdx.x * 256 + threadIdx.x;
  int h = idx >> 12, m = (idx >> 6) & 63, d = idx & 63;
  size_t oq = ((size_t)h * GMAX + m) * DH + d;
  int r = m & 31;
  int pos = ((r & 12) << 1) + ((r & 16) >> 2) + (r & 3);
  size_t ot = ((size_t)h * DH + d) * GMAX + (m & 32) + pos;
  if (m < G) {
    int p = gpos[m];
    int pr = p & 31;
    int ppos = ((pr & 12) << 1) + ((pr & 16) >> 2) + (pr & 3);
    gq[oq]  = f2bf(qF[((size_t)h * SLEN + p) * DH + d] * qscale);
    gk[oq]  = kB[((size_t)h * SLEN + p) * DH + d];
    gvt[ot] = vtB[((size_t)(h * 64 + (p >> 6)) * 64 + d) * 64 + (p & 32) + ppos];
  } else {
    gq[oq] = 0; gk[oq] = 0; gvt[ot] = 0;
  }
}

// ---------------- unified attention: LDS-staged, 3-buffer depth-2 pipeline ----------------
// 1152 blocks x 256 thr. wg = XCD-swizzled; wg%9==0 -> global-rows block (128), else local (1024).
// Local: 64 queries (4 waves x 16q), <=10 tiles (incl gtile). Glob: (head, split/8), 8 tiles,
// every wave computes every tile; partials to workspace.
// Pipeline: iter p = { vmcnt(4); s_barrier; stage(p+2)->buf[(p+2)%3]; compute(p) } — loads
// get 2 phases to land, 1 barrier/phase.
__global__ __launch_bounds__(256) void lf_attn(
    const float* __restrict__ qF, const u16* __restrict__ kB, const u16* __restrict__ vtB,
    const u16* __restrict__ gkB, const u16* __restrict__ gqB, const u16* __restrict__ gvtB,
    const unsigned char* __restrict__ gmskA, const unsigned char* __restrict__ mskA,
    const unsigned char* __restrict__ cleanA, const int* __restrict__ nGp,
    float* __restrict__ out, float* __restrict__ pAcc, float* __restrict__ pL, float qscale) {
  __shared__ __align__(16) u16 sK[3][4096];
  __shared__ __align__(16) u16 sV[3][4096];

  const int tid  = threadIdx.x;
  const int wv   = tid >> 6;
  const int lane = tid & 63;
  const int ql   = lane & 15;
  const int g    = lane >> 4;
  const float NEGV = -1e30f;
  const float MEXP = 24.0f;
  const int G = imin(nGp[0], GMAX);

  const int wg = ((int)blockIdx.x & 7) * 144 + ((int)blockIdx.x >> 3);
  const bool glob = (wg % 9) == 0;

  // per-lane swizzled LDS offsets (elements); same table serves K and V reads
  int off[4][2];
#pragma unroll
  for (int t = 0; t < 4; ++t)
#pragma unroll
    for (int c = 0; c < 2; ++c) {
      int row = 16 * t + ql;
      off[t][c] = (row * 8 + ((c * 4 + g) ^ (row & 7))) * 8;
    }

  f32x4 acc[4];
#pragma unroll
  for (int i = 0; i < 4; ++i) acc[i] = (f32x4){0.f, 0.f, 0.f, 0.f};
  f32x4 lsv = (f32x4){0.f, 0.f, 0.f, 0.f};
  bf16x8 qf0, qf1;

  int h, s0w = 0, sq = 0, t0, nPh, qg = 0, splitIdx = 0;
  int lo_w = 0, hi_w = 0;
  bool hasG = false;
  const u16 *gks = nullptr, *gvs = nullptr;

  if (!glob) {
    int lid = wg - wg / 9 - 1;           // 0..1023
    h = lid >> 6;
    int qblk = lid & 63;
    int s0 = qblk << 6;                  // 64 queries per block
    s0w = s0 + 16 * wv; sq = s0w + ql;
    t0 = imax(0, qblk - 4);
    int t1 = imin(63, qblk + 4);
    nPh = t1 - t0 + 1;
    hasG = (G > 0);
    lo_w = imax(t0, (s0w - WW) >> 6);
    hi_w = imin(t1, (s0w + 15 + WW) >> 6);
    // Q: f32 -> bf16 in-register, scaled
    const float* qr = qF + ((size_t)h * SLEN + sq) * DH;
    float4 a0 = *(const float4*)(qr + 8 * g);
    float4 a1 = *(const float4*)(qr + 8 * g + 4);
    float4 b0 = *(const float4*)(qr + 32 + 8 * g);
    float4 b1 = *(const float4*)(qr + 32 + 8 * g + 4);
    union { u32 w[4]; bf16x8 v; } uq;
    uq.w[0] = cvtpk(a0.x * qscale, a0.y * qscale);
    uq.w[1] = cvtpk(a0.z * qscale, a0.w * qscale);
    uq.w[2] = cvtpk(a1.x * qscale, a1.y * qscale);
    uq.w[3] = cvtpk(a1.z * qscale, a1.w * qscale);
    qf0 = uq.v;
    uq.w[0] = cvtpk(b0.x * qscale, b0.y * qscale);
    uq.w[1] = cvtpk(b0.z * qscale, b0.w * qscale);
    uq.w[2] = cvtpk(b1.x * qscale, b1.y * qscale);
    uq.w[3] = cvtpk(b1.z * qscale, b1.w * qscale);
    qf1 = uq.v;
    gks = gkB + (size_t)h * GMAX * DH;
    gvs = gvtB + (size_t)h * 4096;
  } else {
    int gb = wg / 9;                     // 0..127
    h = gb >> 3; splitIdx = gb & 7;
    qg = wv * 16 + ql;
    t0 = splitIdx * 8; nPh = 8;
    const u16* qRow = gqB + ((size_t)h * GMAX + qg) * DH;
    qf0 = *(const bf16x8*)(qRow + 8 * g);
    qf1 = *(const bf16x8*)(qRow + 32 + 8 * g);
  }
  const u16* kbase = kB  + (size_t)h * 64 * 4096;
  const u16* vbase = vtB + (size_t)h * 64 * 4096;
  const int totPh = nPh + (hasG ? 1 : 0);

  // stage phase p into buffer b: 2 K-instrs + 2 V-instrs per wave (1KB each), src pre-swizzled
  auto stage = [&](int p, int b) {
    const u16 *ks, *vs;
    if (hasG && p == 0) { ks = gks; vs = gvs; }
    else {
      int tv = t0 + p - (hasG ? 1 : 0);
      ks = kbase + (size_t)tv * 4096;
      vs = vbase + (size_t)tv * 4096;
    }
#pragma unroll
    for (int j = 0; j < 2; ++j) {
      int gran = (wv * 2 + j) * 64 + lane;
      int sg = gran ^ ((gran >> 3) & 7);
      gload16(ks + (size_t)sg * 8, &sK[b][(wv * 2 + j) * 512]);
      gload16(vs + (size_t)sg * 8, &sV[b][(wv * 2 + j) * 512]);
    }
  };

  auto compute = [&](int p, int buf) {
    const bool isg = (hasG && p == 0);
    const int tv = t0 + p - (hasG ? 1 : 0);
    const int kb = tv * 64;
    bool doC = glob ? true : (isg || (tv >= lo_w && tv <= hi_w));
    if (!doC) return;
    const u16* sk = &sK[buf][0];
    const u16* sv = &sV[buf][0];
    f32x4 sc[4];
#pragma unroll
    for (int t = 0; t < 4; ++t) sc[t] = (f32x4){0.f, 0.f, 0.f, 0.f};
#pragma unroll
    for (int t = 0; t < 4; ++t) {
      bf16x8 a0 = *(const bf16x8*)(sk + off[t][0]);
      bf16x8 a1 = *(const bf16x8*)(sk + off[t][1]);
      sc[t] = MFMA16(a0, qf0, sc[t]);
      sc[t] = MFMA16(a1, qf1, sc[t]);
    }
    f32x4 pv[4];
    if (isg) {
#pragma unroll
      for (int t = 0; t < 4; ++t) {
        u32 mw = *(const u32*)(gmskA + 16 * t + 4 * g);
#pragma unroll
        for (int i = 0; i < 4; ++i) {
          float s = ((mw >> (8 * i)) & 1) ? sc[t][i] : NEGV;
          pv[t][i] = __builtin_amdgcn_exp2f(s - MEXP);
        }
      }
    } else if (glob) {
      u16 cw = *(const u16*)(cleanA + (kb >> 5));
      if (cw & (cw >> 8) & 2) {
#pragma unroll
        for (int t = 0; t < 4; ++t)
#pragma unroll
          for (int i = 0; i < 4; ++i)
            pv[t][i] = __builtin_amdgcn_exp2f(sc[t][i] - MEXP);
      } else {
#pragma unroll
        for (int t = 0; t < 4; ++t) {
          u32 mw = *(const u32*)(mskA + kb + 16 * t + 4 * g);
#pragma unroll
          for (int i = 0; i < 4; ++i) {
            float s = ((mw >> (8 * i)) & 1) ? sc[t][i] : NEGV;
            pv[t][i] = __builtin_amdgcn_exp2f(s - MEXP);
          }
        }
      }
    } else {
      u16 cw = *(const u16*)(cleanA + (kb >> 5));
      bool cl = ((cw & (cw >> 8) & 1) != 0) &&
                (kb >= s0w + 15 - WW) && (kb + 63 <= s0w + WW);
      if (cl) {
#pragma unroll
        for (int t = 0; t < 4; ++t)
#pragma unroll
          for (int i = 0; i < 4; ++i)
            pv[t][i] = __builtin_amdgcn_exp2f(sc[t][i] - MEXP);
      } else {
#pragma unroll
        for (int t = 0; t < 4; ++t) {
          u32 mw = *(const u32*)(mskA + kb + 16 * t + 4 * g);
#pragma unroll
          for (int i = 0; i < 4; ++i) {
            int kkey = kb + 16 * t + 4 * g + i;
            bool vok = (((mw >> (8 * i)) & 3) == 1) && (kkey >= sq - WW) && (kkey <= sq + WW);
            float s = vok ? sc[t][i] : NEGV;
            pv[t][i] = __builtin_amdgcn_exp2f(s - MEXP);
          }
        }
      }
    }
    lsv += pv[0] + pv[1] + pv[2] + pv[3];
#pragma unroll
    for (int s2 = 0; s2 < 2; ++s2) {
      union { u32 w[4]; bf16x8 v8; } u;
      u.w[0] = cvtpk(pv[2 * s2][0], pv[2 * s2][1]);
      u.w[1] = cvtpk(pv[2 * s2][2], pv[2 * s2][3]);
      u.w[2] = cvtpk(pv[2 * s2 + 1][0], pv[2 * s2 + 1][1]);
      u.w[3] = cvtpk(pv[2 * s2 + 1][2], pv[2 * s2 + 1][3]);
#pragma unroll
      for (int dt = 0; dt < 4; ++dt) {
        bf16x8 vf = *(const bf16x8*)(sv + off[dt][s2]);
        acc[dt] = MFMA16(vf, u.v8, acc[dt]);
      }
    }
  };

  // ---- 3-buffer, depth-2 pipeline; ONE barrier per phase ----
  stage(0, 0);
  if (totPh > 1) stage(1, 1);
  int cur = 0;
  for (int p = 0; p < totPh; ++p) {
    if (p + 1 < totPh) {
      asm volatile("s_waitcnt vmcnt(4)" ::: "memory");
    } else {
      asm volatile("s_waitcnt vmcnt(0)" ::: "memory");
    }
    __builtin_amdgcn_s_barrier();
    __builtin_amdgcn_sched_barrier(0);
    if (p + 2 < totPh) {
      int nb = cur + 2; if (nb >= 3) nb -= 3;
      stage(p + 2, nb);
    }
    compute(p, cur);
    ++cur; if (cur == 3) cur = 0;
  }

  float lsum = lsv[0] + lsv[1] + lsv[2] + lsv[3];
  lsum += __shfl_xor(lsum, 16);
  lsum += __shfl_xor(lsum, 32);

  if (!glob) {
    float inv = 1.f / lsum;
    bool skip = (mskA[sq] & 4) != 0;
    if (!skip) {
      float* orow = out + ((size_t)h * SLEN + sq) * DH;
#pragma unroll
      for (int dt = 0; dt < 4; ++dt) {
        f32x4 o = acc[dt] * inv;
        *(f32x4*)(orow + dt * 16 + 4 * g) = o;
      }
    }
  } else {
    float* pa = pAcc + ((size_t)(h * 8 + splitIdx) * 64 + qg) * 64;
#pragma unroll
    for (int dt = 0; dt < 4; ++dt)
      *(f32x4*)&pa[dt * 16 + 4 * g] = acc[dt];
    if (g == 0) pL[(h * 8 + splitIdx) * 64 + qg] = lsum;
  }
}

// ---------------- merge the 8 key-splits of global rows ----------------
__global__ void lf_gmerge(const float* __restrict__ pAcc, const float* __restrict__ pL,
                          const int* __restrict__ gpos, const int* __restrict__ nGp,
                          float* __restrict__ out) {
  const int G = imin(nGp[0], GMAX);
  int h = blockIdx.x;
  int tid = threadIdx.x;
#pragma unroll
  for (int it = 0; it < 4; ++it) {
    int v = tid + it * 256;            // 0..1023
    int q = v >> 4, d4 = (v & 15) << 2;
    if (q >= G) continue;
    float L = 0.f;
    f32x4 a = (f32x4){0.f, 0.f, 0.f, 0.f};
#pragma unroll
    for (int s = 0; s < 8; ++s) {
      L += pL[(h * 8 + s) * 64 + q];
      a += *(const f32x4*)&pAcc[((size_t)(h * 8 + s) * 64 + q) * 64 + d4];
    }
    *(f32x4*)&out[((size_t)h * SLEN + gpos[q]) * DH + d4] = a * (1.f / L);
  }
}

// ---------------- launch ----------------
extern "C" void kernel_launch(void* const* d_in, const int* in_sizes, int n_in,
                              void* d_out, int out_size, void* d_ws, size_t ws_size,
                              hipStream_t stream) {
  const float* q = (const float*)d_in[0];
  const float* k = (const float*)d_in[1];
  const float* v = (const float*)d_in[2];
  const int* gmask = (const int*)d_in[3];
  const int* pmask = (const int*)d_in[4];
  const int* nGp = (const int*)d_in[5];
  float* out = (float*)d_out;
  char* ws = (char*)d_ws;

  constexpr size_t NEL = (size_t)NH * SLEN * DH;
  constexpr size_t OFF_KBF  = 0;
  constexpr size_t OFF_VTBF = OFF_KBF + NEL * 2;
  constexpr size_t OFF_GK   = OFF_VTBF + NEL * 2 + 256;
  constexpr size_t OFF_GQ   = OFF_GK + (size_t)NH * GMAX * DH * 2;
  constexpr size_t OFF_GVT  = OFF_GQ + (size_t)NH * GMAX * DH * 2;
  constexpr size_t OFF_GPOS = OFF_GVT + (size_t)NH * DH * GMAX * 2;
  constexpr size_t OFF_GMSK = OFF_GPOS + 256;
  constexpr size_t OFF_MSK  = OFF_GMSK + 64;
  constexpr size_t OFF_CLEAN = OFF_MSK + SLEN + 64;
  constexpr size_t OFF_PACC = OFF_CLEAN + 256;
  constexpr size_t OFF_PL   = OFF_PACC + (size_t)NH * 8 * 64 * 64 * 4;

  u16* kB  = (u16*)(ws + OFF_KBF);
  u16* vtB = (u16*)(ws + OFF_VTBF);
  u16* gk  = (u16*)(ws + OFF_GK);
  u16* gq  = (u16*)(ws + OFF_GQ);
  u16* gvt = (u16*)(ws + OFF_GVT);
  int* gpos = (int*)(ws + OFF_GPOS);
  unsigned char* gmsk = (unsigned char*)(ws + OFF_GMSK);
  unsigned char* msk  = (unsigned char*)(ws + OFF_MSK);
  unsigned char* clean = (unsigned char*)(ws + OFF_CLEAN);
  float* pAcc = (float*)(ws + OFF_PACC);
  float* pL   = (float*)(ws + OFF_PL);

  const float qscale = 0.125f * 1.4426950408889634f;  // 1/sqrt(64) * log2(e)

  lf_prep1<<<3073, 256, 0, stream>>>(k, v, gmask, pmask, nGp,
                                     kB, vtB, gpos, gmsk, msk, clean);
  lf_gather<<<256, 256, 0, stream>>>(q, kB, vtB, gpos, nGp, gq, gk, gvt, qscale);
  lf_attn<<<1152, 256, 0, stream>>>(q, kB, vtB, gk, gq, gvt, gmsk, msk, clean,
                                    nGp, out, pAcc, pL, qscale);
  lf_gmerge<<<NH, 256, 0, stream>>>(pAcc, pL, gpos, nGp, out);
}

// Round 8
// 53.367 us; speedup vs baseline: 2.5480x; 1.0353x over previous
//
#include <hip/hip_runtime.h>
#include <hip/hip_bf16.h>

#define SLEN 4096
#define NH   16
#define DH   64
#define WW   256
#define GMAX 64

typedef unsigned short u16;
typedef unsigned int   u32;
typedef unsigned long long u64;
typedef __attribute__((ext_vector_type(8))) short bf16x8;
typedef __attribute__((ext_vector_type(4))) float f32x4;

#define MFMA16(a,b,c) __builtin_amdgcn_mfma_f32_16x16x32_bf16((a),(b),(c),0,0,0)

static __device__ __forceinline__ int imin(int a, int b) { return a < b ? a : b; }
static __device__ __forceinline__ int imax(int a, int b) { return a > b ? a : b; }

__device__ __forceinline__ u32 cvtpk(float lo, float hi) {
  u32 r;
  asm("v_cvt_pk_bf16_f32 %0, %1, %2" : "=v"(r) : "v"(lo), "v"(hi));
  return r;
}
__device__ __forceinline__ u16 f2bf(float x) {
  u32 u = __float_as_uint(x);
  u32 r = (u + 0x7fffu + ((u >> 16) & 1u)) >> 16;
  return (u16)r;
}

// async global->LDS, 16B per lane; lds base must be wave-uniform
__device__ __forceinline__ void gload16(const u16* src, u16* lds_base) {
  __builtin_amdgcn_global_load_lds((const __attribute__((address_space(1))) u32*)src,
                                   (__attribute__((address_space(3))) u32*)lds_base,
                                   16, 0, 0);
}

// ---------------- prep1: k bf16-convert + V transpose (tiled, σ-permuted) + meta ----------
__global__ __launch_bounds__(256) void lf_prep1(
    const float* __restrict__ k, const float* __restrict__ v,
    const int* __restrict__ gmask, const int* __restrict__ pmask, const int* __restrict__ nGp,
    u16* __restrict__ kB, u16* __restrict__ vtB,
    int* __restrict__ gpos, unsigned char* __restrict__ gmsk,
    unsigned char* __restrict__ msk, unsigned char* __restrict__ cleanmap) {
  const int bid = blockIdx.x;
  const int tid = threadIdx.x;
  if (bid < 2048) {
    int i = (bid * 256 + tid) * 8;
    float4 v0 = *(const float4*)(k + i);
    float4 v1 = *(const float4*)(k + i + 4);
    uint4 w;
    w.x = cvtpk(v0.x, v0.y);
    w.y = cvtpk(v0.z, v0.w);
    w.z = cvtpk(v1.x, v1.y);
    w.w = cvtpk(v1.z, v1.w);
    *(uint4*)(kB + i) = w;
    return;
  }
  if (bid < 3072) {
    __shared__ float t[64][65];
    int b = bid - 2048;
    int h = b >> 6, s0 = (b & 63) << 6;
    int tile = h * 64 + (b & 63);
    int r = tid >> 2, c0 = (tid & 3) << 4;
    const float* src = v + ((size_t)h * SLEN + s0 + r) * DH + c0;
#pragma unroll
    for (int j = 0; j < 16; j += 4) {
      float4 a = *(const float4*)(src + j);
      t[r][c0 + j]     = a.x;
      t[r][c0 + j + 1] = a.y;
      t[r][c0 + j + 2] = a.z;
      t[r][c0 + j + 3] = a.w;
    }
    __syncthreads();
    int d = tid >> 2, j0 = (tid & 3) << 4;
    int grp  = j0 & 32;
    int half = (j0 & 16) ? 4 : 0;
    u16* dst = vtB + ((size_t)tile * 64 + d) * 64 + grp;
#pragma unroll
    for (int q4 = 0; q4 < 4; ++q4) {
      uint2 val;
      val.x = cvtpk(t[j0 + 4 * q4 + 0][d], t[j0 + 4 * q4 + 1][d]);
      val.y = cvtpk(t[j0 + 4 * q4 + 2][d], t[j0 + 4 * q4 + 3][d]);
      *(uint2*)(dst + 8 * q4 + half) = val;
    }
    return;
  }
  // ---- meta block ----
  const int G = imin(nGp[0], GMAX);
  for (int s = tid; s < SLEN; s += 256) {
    unsigned char b = (unsigned char)((pmask[s] ? 1 : 0) | (gmask[s] ? 2 : 0));
    msk[s] = b;
  }
  for (int s = SLEN + tid; s < SLEN + 64; s += 256) msk[s] = 0;
  __syncthreads();
  if (tid < 64) {
    int lane = tid;
    if (lane < GMAX) gmsk[lane] = 0;
    int cnt = 0;
    for (int c = 0; c < SLEN / 64 && cnt < G; ++c) {
      int s = c * 64 + lane;
      bool isg = gmask[s] != 0;
      u64 b = __ballot(isg);
      int rank = cnt + (int)__popcll(b & ((1ull << lane) - 1ull));
      if (isg && rank < G) gpos[rank] = s;
      cnt += (int)__popcll(b);
    }
    if (cnt < G) {
      int fill = cnt;
      for (int c = 0; c < SLEN / 64 && fill < G; ++c) {
        int s = c * 64 + lane;
        bool non = gmask[s] == 0;
        u64 b = __ballot(non);
        int rank = fill + (int)__popcll(b & ((1ull << lane) - 1ull));
        if (non && rank < G) gpos[rank] = s;
        fill += (int)__popcll(b);
      }
    }
  }
  __syncthreads();
  if (tid < 64) {
    if (tid < G) {
      int p = gpos[tid];
      gmsk[tid] = (unsigned char)(pmask[p] ? 1 : 0);
      msk[p] = (unsigned char)(msk[p] | 4);
    }
  } else if (tid >= 128) {
    int c = tid - 128;
    if (c < SLEN / 32) {
      unsigned char ok1 = 1, ok2 = 1;
      for (int kk = 0; kk < 32; ++kk) {
        unsigned char b = msk[c * 32 + kk];
        ok1 &= (unsigned char)(((b & 3) == 1) ? 1 : 0);
        ok2 &= (unsigned char)(b & 1);
      }
      cleanmap[c] = (unsigned char)(ok1 | (ok2 << 1));
    }
  }
}

// ---------------- prep2: gather global K/Q rows and Vt cols (tiled source) ----------------
__global__ void lf_gather(const float* __restrict__ qF, const u16* __restrict__ kB,
                          const u16* __restrict__ vtB, const int* __restrict__ gpos,
                          const int* __restrict__ nGp,
                          u16* __restrict__ gq, u16* __restrict__ gk, u16* __restrict__ gvt,
                          float qscale) {
  const int G = imin(nGp[0], GMAX);
  int idx = blockIdx.x * 256 + threadIdx.x;
  int h = idx >> 12, m = (idx >> 6) & 63, d = idx & 63;
  size_t oq = ((size_t)h * GMAX + m) * DH + d;
  int r = m & 31;
  int pos = ((r & 12) << 1) + ((r & 16) >> 2) + (r & 3);
  size_t ot = ((size_t)h * DH + d) * GMAX + (m & 32) + pos;
  if (m < G) {
    int p = gpos[m];
    int pr = p & 31;
    int ppos = ((pr & 12) << 1) + ((pr & 16) >> 2) + (pr & 3);
    gq[oq]  = f2bf(qF[((size_t)h * SLEN + p) * DH + d] * qscale);
    gk[oq]  = kB[((size_t)h * SLEN + p) * DH + d];
    gvt[ot] = vtB[((size_t)(h * 64 + (p >> 6)) * 64 + d) * 64 + (p & 32) + ppos];
  } else {
    gq[oq] = 0; gk[oq] = 0; gvt[ot] = 0;
  }
}

// ---------------- unified attention: LDS-staged, metadata pre-staged ----------------
// 1152 blocks x 256 thr. wg = XCD-swizzled; wg%9==0 -> global-rows block (128), else local (1024).
// NO global loads inside the phase loop except the 4 stage gload_lds per wave:
// per-tile clean flags live in a ballot-built u64 register; msk/gmsk bytes live in LDS.
__global__ __launch_bounds__(256) void lf_attn(
    const float* __restrict__ qF, const u16* __restrict__ kB, const u16* __restrict__ vtB,
    const u16* __restrict__ gkB, const u16* __restrict__ gqB, const u16* __restrict__ gvtB,
    const unsigned char* __restrict__ gmskA, const unsigned char* __restrict__ mskA,
    const unsigned char* __restrict__ cleanA, const int* __restrict__ nGp,
    float* __restrict__ out, float* __restrict__ pAcc, float* __restrict__ pL, float qscale) {
  __shared__ __align__(16) u16 sK[2][4096];
  __shared__ __align__(16) u16 sV[2][4096];
  __shared__ u32 sMsk[192];     // block's msk byte range (<=704B used)
  __shared__ u32 sGm[16];       // gmsk bytes (64B)

  const int tid  = threadIdx.x;
  const int wv   = tid >> 6;
  const int lane = tid & 63;
  const int ql   = lane & 15;
  const int g    = lane >> 4;
  const float NEGV = -1e30f;
  const float MEXP = 24.0f;
  const int G = imin(nGp[0], GMAX);

  const int wg = ((int)blockIdx.x & 7) * 144 + ((int)blockIdx.x >> 3);
  const bool glob = (wg % 9) == 0;

  int off[4][2];
#pragma unroll
  for (int t = 0; t < 4; ++t)
#pragma unroll
    for (int c = 0; c < 2; ++c) {
      int row = 16 * t + ql;
      off[t][c] = (row * 8 + ((c * 4 + g) ^ (row & 7))) * 8;
    }

  f32x4 acc[4];
#pragma unroll
  for (int i = 0; i < 4; ++i) acc[i] = (f32x4){0.f, 0.f, 0.f, 0.f};
  f32x4 lsv = (f32x4){0.f, 0.f, 0.f, 0.f};
  bf16x8 qf0, qf1;

  int h, s0w = 0, sq = 0, t0, nMain, qg = 0, splitIdx = 0;
  int lo_w = 0, hi_w = 0;
  bool hasG = false;
  const u16 *gks = nullptr, *gvs = nullptr;

  if (!glob) {
    int lid = wg - wg / 9 - 1;           // 0..1023
    h = lid >> 6;
    int qblk = lid & 63;
    int s0 = qblk << 6;
    s0w = s0 + 16 * wv; sq = s0w + ql;
    t0 = imax(0, qblk - 4);
    int t1 = imin(63, qblk + 4);
    nMain = t1 - t0 + 1;
    hasG = (G > 0);
    lo_w = imax(t0, (s0w - WW) >> 6);
    hi_w = imin(t1, (s0w + 15 + WW) >> 6);
    const float* qr = qF + ((size_t)h * SLEN + sq) * DH;
    float4 a0 = *(const float4*)(qr + 8 * g);
    float4 a1 = *(const float4*)(qr + 8 * g + 4);
    float4 b0 = *(const float4*)(qr + 32 + 8 * g);
    float4 b1 = *(const float4*)(qr + 32 + 8 * g + 4);
    union { u32 w[4]; bf16x8 v; } uq;
    uq.w[0] = cvtpk(a0.x * qscale, a0.y * qscale);
    uq.w[1] = cvtpk(a0.z * qscale, a0.w * qscale);
    uq.w[2] = cvtpk(a1.x * qscale, a1.y * qscale);
    uq.w[3] = cvtpk(a1.z * qscale, a1.w * qscale);
    qf0 = uq.v;
    uq.w[0] = cvtpk(b0.x * qscale, b0.y * qscale);
    uq.w[1] = cvtpk(b0.z * qscale, b0.w * qscale);
    uq.w[2] = cvtpk(b1.x * qscale, b1.y * qscale);
    uq.w[3] = cvtpk(b1.z * qscale, b1.w * qscale);
    qf1 = uq.v;
    gks = gkB + (size_t)h * GMAX * DH;
    gvs = gvtB + (size_t)h * 4096;
  } else {
    int gb = wg / 9;                     // 0..127
    h = gb >> 3; splitIdx = gb & 7;
    qg = wv * 16 + ql;
    t0 = splitIdx * 8; nMain = 8;
    const u16* qRow = gqB + ((size_t)h * GMAX + qg) * DH;
    qf0 = *(const bf16x8*)(qRow + 8 * g);
    qf1 = *(const bf16x8*)(qRow + 32 + 8 * g);
  }
  const u16* kbase = kB  + (size_t)h * 64 * 4096;
  const u16* vbase = vtB + (size_t)h * 64 * 4096;
  const int totPh = nMain + (hasG ? 1 : 0);

  // per-tile clean bitmask in a register (bit i = tile t0+i clean)
  const unsigned char cmask = glob ? 2 : 1;
  unsigned char cbyte = 0;
  if (lane < nMain) {
    cbyte = (unsigned char)(cleanA[2 * (t0 + lane)] & cleanA[2 * (t0 + lane) + 1]);
  }
  const u64 cbits = __ballot((cbyte & cmask) != 0);

  auto stage = [&](int p, int b) {
    const u16 *ks, *vs;
    if (hasG && p == 0) { ks = gks; vs = gvs; }
    else {
      int tv = t0 + p - (hasG ? 1 : 0);
      ks = kbase + (size_t)tv * 4096;
      vs = vbase + (size_t)tv * 4096;
    }
#pragma unroll
    for (int j = 0; j < 2; ++j) {
      int gran = (wv * 2 + j) * 64 + lane;
      int sg = gran ^ ((gran >> 3) & 7);
      gload16(ks + (size_t)sg * 8, &sK[b][(wv * 2 + j) * 512]);
      gload16(vs + (size_t)sg * 8, &sV[b][(wv * 2 + j) * 512]);
    }
  };

  auto compute = [&](int p, int buf) {
    const bool isg = (hasG && p == 0);
    const int idx = p - (hasG ? 1 : 0);
    const int tv = t0 + idx;
    const int kb = tv * 64;
    bool doC = glob ? true : (isg || (tv >= lo_w && tv <= hi_w));
    if (!doC) return;
    const u16* sk = &sK[buf][0];
    const u16* sv = &sV[buf][0];
    f32x4 sc[4];
#pragma unroll
    for (int t = 0; t < 4; ++t) sc[t] = (f32x4){0.f, 0.f, 0.f, 0.f};
#pragma unroll
    for (int t = 0; t < 4; ++t) {
      bf16x8 a0 = *(const bf16x8*)(sk + off[t][0]);
      bf16x8 a1 = *(const bf16x8*)(sk + off[t][1]);
      sc[t] = MFMA16(a0, qf0, sc[t]);
      sc[t] = MFMA16(a1, qf1, sc[t]);
    }
    f32x4 pv[4];
    if (isg) {
#pragma unroll
      for (int t = 0; t < 4; ++t) {
        u32 mw = sGm[4 * t + g];
#pragma unroll
        for (int i = 0; i < 4; ++i) {
          float s = ((mw >> (8 * i)) & 1) ? sc[t][i] : NEGV;
          pv[t][i] = __builtin_amdgcn_exp2f(s - MEXP);
        }
      }
    } else {
      bool cl = ((cbits >> idx) & 1) != 0;
      if (!glob) cl = cl && (kb >= s0w + 15 - WW) && (kb + 63 <= s0w + WW);
      if (cl) {
#pragma unroll
        for (int t = 0; t < 4; ++t)
#pragma unroll
          for (int i = 0; i < 4; ++i)
            pv[t][i] = __builtin_amdgcn_exp2f(sc[t][i] - MEXP);
      } else if (glob) {
#pragma unroll
        for (int t = 0; t < 4; ++t) {
          u32 mw = sMsk[(idx << 4) + 4 * t + g];
#pragma unroll
          for (int i = 0; i < 4; ++i) {
            float s = ((mw >> (8 * i)) & 1) ? sc[t][i] : NEGV;
            pv[t][i] = __builtin_amdgcn_exp2f(s - MEXP);
          }
        }
      } else {
#pragma unroll
        for (int t = 0; t < 4; ++t) {
          u32 mw = sMsk[(idx << 4) + 4 * t + g];
#pragma unroll
          for (int i = 0; i < 4; ++i) {
            int kkey = kb + 16 * t + 4 * g + i;
            bool vok = (((mw >> (8 * i)) & 3) == 1) && (kkey >= sq - WW) && (kkey <= sq + WW);
            float s = vok ? sc[t][i] : NEGV;
            pv[t][i] = __builtin_amdgcn_exp2f(s - MEXP);
          }
        }
      }
    }
    lsv += pv[0] + pv[1] + pv[2] + pv[3];
#pragma unroll
    for (int s2 = 0; s2 < 2; ++s2) {
      union { u32 w[4]; bf16x8 v8; } u;
      u.w[0] = cvtpk(pv[2 * s2][0], pv[2 * s2][1]);
      u.w[1] = cvtpk(pv[2 * s2][2], pv[2 * s2][3]);
      u.w[2] = cvtpk(pv[2 * s2 + 1][0], pv[2 * s2 + 1][1]);
      u.w[3] = cvtpk(pv[2 * s2 + 1][2], pv[2 * s2 + 1][3]);
#pragma unroll
      for (int dt = 0; dt < 4; ++dt) {
        bf16x8 vf = *(const bf16x8*)(sv + off[dt][s2]);
        acc[dt] = MFMA16(vf, u.v8, acc[dt]);
      }
    }
  };

  // ---- prologue: stage(0) + metadata into LDS, one full sync ----
  stage(0, 0);
  {
    int nb = nMain << 4;                 // u32 words of msk needed
    if (tid < nb) sMsk[tid] = *(const u32*)(mskA + (t0 << 6) + (tid << 2));
    if (hasG && tid >= 192 && tid < 208) sGm[tid - 192] = *(const u32*)(gmskA + ((tid - 192) << 2));
  }
  __syncthreads();

  // ---- 2-buffer depth-1 pipeline (R6 skeleton) ----
  for (int p = 0; p < totPh; ++p) {
    if (p + 1 < totPh) {
      stage(p + 1, (p + 1) & 1);
      asm volatile("s_waitcnt vmcnt(4)" ::: "memory");
    } else {
      asm volatile("s_waitcnt vmcnt(0)" ::: "memory");
    }
    __builtin_amdgcn_s_barrier();
    __builtin_amdgcn_sched_barrier(0);
    compute(p, p & 1);
    __builtin_amdgcn_s_barrier();
  }

  float lsum = lsv[0] + lsv[1] + lsv[2] + lsv[3];
  lsum += __shfl_xor(lsum, 16);
  lsum += __shfl_xor(lsum, 32);

  if (!glob) {
    float inv = 1.f / lsum;
    bool skip = (mskA[sq] & 4) != 0;
    if (!skip) {
      float* orow = out + ((size_t)h * SLEN + sq) * DH;
#pragma unroll
      for (int dt = 0; dt < 4; ++dt) {
        f32x4 o = acc[dt] * inv;
        *(f32x4*)(orow + dt * 16 + 4 * g) = o;
      }
    }
  } else {
    float* pa = pAcc + ((size_t)(h * 8 + splitIdx) * 64 + qg) * 64;
#pragma unroll
    for (int dt = 0; dt < 4; ++dt)
      *(f32x4*)&pa[dt * 16 + 4 * g] = acc[dt];
    if (g == 0) pL[(h * 8 + splitIdx) * 64 + qg] = lsum;
  }
}

// ---------------- merge the 8 key-splits of global rows ----------------
__global__ void lf_gmerge(const float* __restrict__ pAcc, const float* __restrict__ pL,
                          const int* __restrict__ gpos, const int* __restrict__ nGp,
                          float* __restrict__ out) {
  const int G = imin(nGp[0], GMAX);
  int h = blockIdx.x;
  int tid = threadIdx.x;
#pragma unroll
  for (int it = 0; it < 4; ++it) {
    int v = tid + it * 256;
    int q = v >> 4, d4 = (v & 15) << 2;
    if (q >= G) continue;
    float L = 0.f;
    f32x4 a = (f32x4){0.f, 0.f, 0.f, 0.f};
#pragma unroll
    for (int s = 0; s < 8; ++s) {
      L += pL[(h * 8 + s) * 64 + q];
      a += *(const f32x4*)&pAcc[((size_t)(h * 8 + s) * 64 + q) * 64 + d4];
    }
    *(f32x4*)&out[((size_t)h * SLEN + gpos[q]) * DH + d4] = a * (1.f / L);
  }
}

// ---------------- launch ----------------
extern "C" void kernel_launch(void* const* d_in, const int* in_sizes, int n_in,
                              void* d_out, int out_size, void* d_ws, size_t ws_size,
                              hipStream_t stream) {
  const float* q = (const float*)d_in[0];
  const float* k = (const float*)d_in[1];
  const float* v = (const float*)d_in[2];
  const int* gmask = (const int*)d_in[3];
  const int* pmask = (const int*)d_in[4];
  const int* nGp = (const int*)d_in[5];
  float* out = (float*)d_out;
  char* ws = (char*)d_ws;

  constexpr size_t NEL = (size_t)NH * SLEN * DH;
  constexpr size_t OFF_KBF  = 0;
  constexpr size_t OFF_VTBF = OFF_KBF + NEL * 2;
  constexpr size_t OFF_GK   = OFF_VTBF + NEL * 2 + 256;
  constexpr size_t OFF_GQ   = OFF_GK + (size_t)NH * GMAX * DH * 2;
  constexpr size_t OFF_GVT  = OFF_GQ + (size_t)NH * GMAX * DH * 2;
  constexpr size_t OFF_GPOS = OFF_GVT + (size_t)NH * DH * GMAX * 2;
  constexpr size_t OFF_GMSK = OFF_GPOS + 256;
  constexpr size_t OFF_MSK  = OFF_GMSK + 64;
  constexpr size_t OFF_CLEAN = OFF_MSK + SLEN + 64;
  constexpr size_t OFF_PACC = OFF_CLEAN + 256;
  constexpr size_t OFF_PL   = OFF_PACC + (size_t)NH * 8 * 64 * 64 * 4;

  u16* kB  = (u16*)(ws + OFF_KBF);
  u16* vtB = (u16*)(ws + OFF_VTBF);
  u16* gk  = (u16*)(ws + OFF_GK);
  u16* gq  = (u16*)(ws + OFF_GQ);
  u16* gvt = (u16*)(ws + OFF_GVT);
  int* gpos = (int*)(ws + OFF_GPOS);
  unsigned char* gmsk = (unsigned char*)(ws + OFF_GMSK);
  unsigned char* msk  = (unsigned char*)(ws + OFF_MSK);
  unsigned char* clean = (unsigned char*)(ws + OFF_CLEAN);
  float* pAcc = (float*)(ws + OFF_PACC);
  float* pL   = (float*)(ws + OFF_PL);

  const float qscale = 0.125f * 1.4426950408889634f;  // 1/sqrt(64) * log2(e)

  lf_prep1<<<3073, 256, 0, stream>>>(k, v, gmask, pmask, nGp,
                                     kB, vtB, gpos, gmsk, msk, clean);
  lf_gather<<<256, 256, 0, stream>>>(q, kB, vtB, gpos, nGp, gq, gk, gvt, qscale);
  lf_attn<<<1152, 256, 0, stream>>>(q, kB, vtB, gk, gq, gvt, gmsk, msk, clean,
                                    nGp, out, pAcc, pL, qscale);
  lf_gmerge<<<NH, 256, 0, stream>>>(pAcc, pL, gpos, nGp, out);
}